// Round 4
// baseline (1474.671 us; speedup 1.0000x reference)
//
#include <hip/hip_runtime.h>
#include <hip/hip_bf16.h>
#include <math.h>

// Problem constants
#define B_   64
#define N_   576
#define D_   768
#define L_   64
#define H_   8
#define HD_  96
#define NB_  (B_*N_)    // 36864 rows
#define ML_  (B_*L_)    // 4096 rows
#define SCALE_ 0.10206207f          // 96^-0.5
#define INV_SQRT_D_ 0.03608439182f  // 1/sqrt(768)

typedef __hip_bfloat16 bf16;
typedef __attribute__((ext_vector_type(8))) short short8v;   // 8 bf16 (4 VGPRs)
typedef __attribute__((ext_vector_type(4))) float floatx4;   // MFMA C/D

__device__ __forceinline__ float u2f(unsigned short u) { return __uint_as_float(((unsigned)u) << 16); }
__device__ __forceinline__ unsigned short f2bu(float f) {
  bf16 h = __float2bfloat16(f);
  return *(unsigned short*)&h;
}

// ---------------------------------------------------------------------------
// K1: LayerNorm1 (fp32 in -> fp32 out) + token_score + row sum-of-squares
// ---------------------------------------------------------------------------
__global__ __launch_bounds__(256) void k_ln1(const float* __restrict__ x,
    const float* __restrict__ g, const float* __restrict__ bt,
    const float* __restrict__ sw, const float* __restrict__ sb,
    float* __restrict__ xn, float* __restrict__ ts, float* __restrict__ sq)
{
  int row = blockIdx.x, tid = threadIdx.x;
  const float* xr = x + (size_t)row * D_;
  float v0 = xr[tid], v1 = xr[tid + 256], v2 = xr[tid + 512];
  __shared__ float r1[256], r2[256];
  r1[tid] = v0 + v1 + v2;
  r2[tid] = v0 * v0 + v1 * v1 + v2 * v2;
  __syncthreads();
  for (int o = 128; o > 0; o >>= 1) {
    if (tid < o) { r1[tid] += r1[tid + o]; r2[tid] += r2[tid + o]; }
    __syncthreads();
  }
  float mean = r1[0] * (1.0f / D_);
  float var  = r2[0] * (1.0f / D_) - mean * mean;
  float rstd = rsqrtf(var + 1e-5f);
  __syncthreads();
  float o0 = (v0 - mean) * rstd * g[tid      ] + bt[tid      ];
  float o1 = (v1 - mean) * rstd * g[tid + 256] + bt[tid + 256];
  float o2 = (v2 - mean) * rstd * g[tid + 512] + bt[tid + 512];
  float* xo = xn + (size_t)row * D_;
  xo[tid] = o0; xo[tid + 256] = o1; xo[tid + 512] = o2;
  r1[tid] = o0 * sw[tid] + o1 * sw[tid + 256] + o2 * sw[tid + 512];
  r2[tid] = o0 * o0 + o1 * o1 + o2 * o2;
  __syncthreads();
  for (int o = 128; o > 0; o >>= 1) {
    if (tid < o) { r1[tid] += r1[tid + o]; r2[tid] += r2[tid + o]; }
    __syncthreads();
  }
  if (tid == 0) { ts[row] = r1[0] + sb[0]; sq[row] = r2[0]; }
}

// ---------------------------------------------------------------------------
// K2: pairwise distance matrix (fp32 — feeds discrete clustering; keep exact)
// 128x128 tile, 8x8 microtile, upper-tri over 5 padded tiles (15 pairs).
// LDS shifted layout: element col m at position m + 4*(m>>5) -> B-frag reads
// are 2-way (free); row width 140 floats.
// grid (15, B_), block 256
// ---------------------------------------------------------------------------
__global__ __launch_bounds__(256) void k_dm(const float* __restrict__ xn,
    const float* __restrict__ sq, float* __restrict__ dm)
{
  int b = blockIdx.y;
  int ti, tj;
  {
    int p = blockIdx.x, row = 0, rem = 5;
    while (p >= rem) { p -= rem; rem--; row++; }
    ti = row; tj = row + p;
  }
  __shared__ float AsT[16][140];
  __shared__ float BsT[16][140];
  int tid = threadIdx.x;
  int ty = tid >> 4, tx = tid & 15;
  int am = tid >> 1, ah = (tid & 1) * 8;
  int pa = am + ((am >> 5) << 2);          // shifted store column
  int ra = ti * 128 + am; if (ra > 575) ra = 575;
  int rb = tj * 128 + am; if (rb > 575) rb = 575;
  int gpa = ty * 8 + ((ty >> 2) << 2);     // shifted read pos for A group
  int gpb = tx * 8 + ((tx >> 2) << 2);     // shifted read pos for B group
  const float* Xb = xn + (size_t)b * N_ * D_;
  const float* Arow = Xb + (size_t)ra * D_ + ah;
  const float* Brow = Xb + (size_t)rb * D_ + ah;
  float acc[8][8] = {};
  for (int kt = 0; kt < D_; kt += 16) {
    float4 a0 = *(const float4*)(Arow + kt);
    float4 a1 = *(const float4*)(Arow + kt + 4);
    float4 b0 = *(const float4*)(Brow + kt);
    float4 b1 = *(const float4*)(Brow + kt + 4);
    __syncthreads();
    AsT[ah + 0][pa] = a0.x; AsT[ah + 1][pa] = a0.y; AsT[ah + 2][pa] = a0.z; AsT[ah + 3][pa] = a0.w;
    AsT[ah + 4][pa] = a1.x; AsT[ah + 5][pa] = a1.y; AsT[ah + 6][pa] = a1.z; AsT[ah + 7][pa] = a1.w;
    BsT[ah + 0][pa] = b0.x; BsT[ah + 1][pa] = b0.y; BsT[ah + 2][pa] = b0.z; BsT[ah + 3][pa] = b0.w;
    BsT[ah + 4][pa] = b1.x; BsT[ah + 5][pa] = b1.y; BsT[ah + 6][pa] = b1.z; BsT[ah + 7][pa] = b1.w;
    __syncthreads();
#pragma unroll
    for (int kk = 0; kk < 16; ++kk) {
      float4 av0 = *(const float4*)&AsT[kk][gpa];
      float4 av1 = *(const float4*)&AsT[kk][gpa + 4];
      float4 bv0 = *(const float4*)&BsT[kk][gpb];
      float4 bv1 = *(const float4*)&BsT[kk][gpb + 4];
      float aR[8] = {av0.x, av0.y, av0.z, av0.w, av1.x, av1.y, av1.z, av1.w};
      float bC[8] = {bv0.x, bv0.y, bv0.z, bv0.w, bv1.x, bv1.y, bv1.z, bv1.w};
#pragma unroll
      for (int r = 0; r < 8; ++r)
#pragma unroll
        for (int c = 0; c < 8; ++c) acc[r][c] += aR[r] * bC[c];
    }
  }
  const float* sqb = sq + b * N_;
  float* dmb = dm + (size_t)b * N_ * N_;
  int gi0 = ti * 128 + ty * 8, gj0 = tj * 128 + tx * 8;
#pragma unroll
  for (int r = 0; r < 8; ++r) {
    int gi = gi0 + r;
    if (gi >= N_) continue;
    float si = sqb[gi];
#pragma unroll
    for (int c = 0; c < 8; ++c) {
      int gj = gj0 + c;
      if (gj >= N_) continue;
      float d = si + sqb[gj] - 2.0f * acc[r][c];
      d = sqrtf(fmaxf(d, 0.0f)) * INV_SQRT_D_;
      dmb[(size_t)gi * N_ + gj] = d;
      dmb[(size_t)gj * N_ + gi] = d;
    }
  }
}

// ---------------------------------------------------------------------------
// K3: kNN density + fused per-batch max (drops the separate k_dmax pass)
// grid NB_, block 64 (one wave per row)
// ---------------------------------------------------------------------------
__global__ __launch_bounds__(64) void k_density(const float* __restrict__ dm,
    const float* __restrict__ noise, float* __restrict__ den,
    float* __restrict__ dmax)
{
  int row = blockIdx.x, lane = threadIdx.x;
  int b = row / N_;
  const float* r = dm + (size_t)row * N_;
  float a0 = 1e30f, a1 = 1e30f, a2 = 1e30f, a3 = 1e30f, a4 = 1e30f;
  float mx = 0.0f;
  auto ins5 = [&](float xv) {
    a4 = fminf(a4, xv);
    float t;
    t = fminf(a3, a4); a4 = fmaxf(a3, a4); a3 = t;
    t = fminf(a2, a3); a3 = fmaxf(a2, a3); a2 = t;
    t = fminf(a1, a2); a2 = fmaxf(a1, a2); a1 = t;
    t = fminf(a0, a1); a1 = fmaxf(a0, a1); a0 = t;
  };
#pragma unroll
  for (int t = 0; t < 9; ++t) {
    float v = r[lane + 64 * t];
    ins5(v);
    mx = fmaxf(mx, v);
  }
  for (int m = 1; m < 64; m <<= 1) {
    float b0 = __shfl_xor(a0, m), b1 = __shfl_xor(a1, m), b2 = __shfl_xor(a2, m);
    float b3 = __shfl_xor(a3, m), b4 = __shfl_xor(a4, m);
    ins5(b0); ins5(b1); ins5(b2); ins5(b3); ins5(b4);
    mx = fmaxf(mx, __shfl_xor(mx, m));
  }
  if (lane == 0) {
    float ms = (a0 * a0 + a1 * a1 + a2 * a2 + a3 * a3 + a4 * a4) * 0.2f;
    den[row] = expf(-ms) + noise[row] * 1e-6f;
    atomicMax((unsigned int*)(dmax + b), __float_as_uint(mx));
  }
}

// ---------------------------------------------------------------------------
// K5: dist-to-higher-density + score
// ---------------------------------------------------------------------------
__global__ __launch_bounds__(64) void k_dist(const float* __restrict__ dm,
    const float* __restrict__ den, const float* __restrict__ dmax,
    float* __restrict__ score)
{
  int row = blockIdx.x, lane = threadIdx.x;
  int b = row / N_;
  float di = den[row], dx = dmax[b];
  const float* r = dm + (size_t)row * N_;
  const float* db = den + b * N_;
  float m = dx;
#pragma unroll
  for (int t = 0; t < 9; ++t) {
    int j = lane + 64 * t;
    float v = (db[j] > di) ? r[j] : dx;
    m = fminf(m, v);
  }
  for (int msk = 1; msk < 64; msk <<= 1) m = fminf(m, __shfl_xor(m, msk));
  if (lane == 0) score[row] = m * di;
}

// ---------------------------------------------------------------------------
// K6: top-64 scores per batch
// ---------------------------------------------------------------------------
__global__ __launch_bounds__(256) void k_topL(const float* __restrict__ score,
    int* __restrict__ idxd)
{
  int b = blockIdx.x, tid = threadIdx.x;
  __shared__ float s[N_];
  __shared__ float rv[256];
  __shared__ int   ri[256];
  for (int j = tid; j < N_; j += 256) s[j] = score[b * N_ + j];
  __syncthreads();
  for (int it = 0; it < L_; ++it) {
    float bv = -1e30f; int bi = 1 << 30;
    for (int j = tid; j < N_; j += 256) {
      float v = s[j];
      if (v > bv || (v == bv && j < bi)) { bv = v; bi = j; }
    }
    rv[tid] = bv; ri[tid] = bi; __syncthreads();
    for (int o = 128; o > 0; o >>= 1) {
      if (tid < o) {
        float v2 = rv[tid + o]; int i2 = ri[tid + o];
        if (v2 > rv[tid] || (v2 == rv[tid] && i2 < ri[tid])) { rv[tid] = v2; ri[tid] = i2; }
      }
      __syncthreads();
    }
    if (tid == 0) { idxd[b * L_ + it] = ri[0]; s[ri[0]] = -1e30f; }
    __syncthreads();
  }
}

// ---------------------------------------------------------------------------
// K7: assign tokens to nearest center
// ---------------------------------------------------------------------------
__global__ __launch_bounds__(576) void k_assign(const float* __restrict__ dm,
    const int* __restrict__ idxd, int* __restrict__ idxc)
{
  int b = blockIdx.x, n = threadIdx.x;
  __shared__ int ctr[L_];
  if (n < L_) ctr[n] = idxd[b * L_ + n];
  __syncthreads();
  const float* dmb = dm + (size_t)b * N_ * N_;
  float best = 1e30f; int bl = 0;
  for (int l = 0; l < L_; ++l) {
    float v = dmb[(size_t)ctr[l] * N_ + n];
    if (v < best) { best = v; bl = l; }
  }
  idxc[b * N_ + n] = bl;
}

__global__ __launch_bounds__(64) void k_setcenters(const int* __restrict__ idxd,
    int* __restrict__ idxc)
{
  int b = blockIdx.x, l = threadIdx.x;
  idxc[b * N_ + idxd[b * L_ + l]] = l;
}

// ---------------------------------------------------------------------------
// K8: merger (gather form)
// ---------------------------------------------------------------------------
__global__ __launch_bounds__(256) void k_merge(const float* __restrict__ xn,
    const float* __restrict__ ts, const int* __restrict__ idxc,
    float* __restrict__ qin)
{
  int blk = blockIdx.x;
  int b = blk >> 6, l = blk & 63;
  int tid = threadIdx.x;
  const int* ic = idxc + b * N_;
  const float* tsb = ts + b * N_;
  const float* xb = xn + (size_t)b * N_ * D_;
  float a0 = 0.f, a1 = 0.f, a2 = 0.f, wsum = 0.f;
  for (int n = 0; n < N_; ++n) {
    if (ic[n] == l) {
      float w = expf(tsb[n]);
      wsum += w;
      const float* xr = xb + (size_t)n * D_;
      a0 += w * xr[tid]; a1 += w * xr[tid + 256]; a2 += w * xr[tid + 512];
    }
  }
  float inv = 1.0f / (wsum + 1e-6f);
  float* q = qin + (size_t)blk * D_;
  q[tid] = a0 * inv; q[tid + 256] = a1 * inv; q[tid + 512] = a2 * inv;
}

// ---------------------------------------------------------------------------
// Weight transpose + bf16 cast: W[K,N] fp32 -> WT[N,K] bf16
// ---------------------------------------------------------------------------
__global__ __launch_bounds__(256) void k_wt(const float* __restrict__ W,
    bf16* __restrict__ WT, int K, int N)
{
  __shared__ float t[32][33];
  int k0 = blockIdx.x * 32, n0 = blockIdx.y * 32;
  int tid = threadIdx.x;
  int r = tid >> 3, c4 = (tid & 7) * 4;
  float4 v = *(const float4*)(W + (size_t)(k0 + r) * N + n0 + c4);
  t[r][c4] = v.x; t[r][c4 + 1] = v.y; t[r][c4 + 2] = v.z; t[r][c4 + 3] = v.w;
  __syncthreads();
  unsigned short* o = (unsigned short*)WT;
  ushort4 s4;
  s4.x = f2bu(t[c4 + 0][r]); s4.y = f2bu(t[c4 + 1][r]);
  s4.z = f2bu(t[c4 + 2][r]); s4.w = f2bu(t[c4 + 3][r]);
  *(ushort4*)(o + (size_t)(n0 + r) * K + k0 + c4) = s4;
}

// ---------------------------------------------------------------------------
// MFMA GEMM: C[M,N] = epilogue(A[M,K] @ WT[N,K]^T), bf16 MFMA, fp32 accum.
// ---------------------------------------------------------------------------
template<int EPI, int ASRC>
__global__ __launch_bounds__(256) void k_mgemm(const void* __restrict__ Ap_,
    const bf16* __restrict__ Wt, const float* __restrict__ bias,
    const float* __restrict__ res, void* __restrict__ outp,
    int M, int Nd, int Kd)
{
  __shared__ __align__(16) unsigned short As[128 * 40];
  __shared__ __align__(16) unsigned short Bs[128 * 40];
  int tid = threadIdx.x;
  int bm = blockIdx.x * 128, bn = blockIdx.y * 128;
  int wave = tid >> 6, lane = tid & 63;
  int wr = (wave >> 1) * 64, wc = (wave & 1) * 64;
  int mloc = lane & 15, quad = lane >> 4;

  floatx4 acc[4][4];
#pragma unroll
  for (int i = 0; i < 4; ++i)
#pragma unroll
    for (int j = 0; j < 4; ++j)
      acc[i][j] = (floatx4){0.f, 0.f, 0.f, 0.f};

  const unsigned short* Wu = (const unsigned short*)Wt;
  for (int kt = 0; kt < Kd; kt += 32) {
    __syncthreads();
#pragma unroll
    for (int it = 0; it < 2; ++it) {
      int idx = tid + it * 256;          // 0..511
      int r = idx >> 2, c = idx & 3;     // row 0..127, 8-elem chunk 0..3
      uint4 pk;
      if (ASRC == 0) {
        const float* A = (const float*)Ap_;
        const float* ap = A + (size_t)(bm + r) * Kd + kt + c * 8;
        float4 f0 = *(const float4*)ap;
        float4 f1 = *(const float4*)(ap + 4);
        pk.x = (unsigned)f2bu(f0.x) | ((unsigned)f2bu(f0.y) << 16);
        pk.y = (unsigned)f2bu(f0.z) | ((unsigned)f2bu(f0.w) << 16);
        pk.z = (unsigned)f2bu(f1.x) | ((unsigned)f2bu(f1.y) << 16);
        pk.w = (unsigned)f2bu(f1.z) | ((unsigned)f2bu(f1.w) << 16);
      } else {
        const unsigned short* A = (const unsigned short*)Ap_;
        pk = *(const uint4*)(A + (size_t)(bm + r) * Kd + kt + c * 8);
      }
      *(uint4*)&As[r * 40 + c * 8] = pk;
      uint4 wb = *(const uint4*)(Wu + (size_t)(bn + r) * Kd + kt + c * 8);
      *(uint4*)&Bs[r * 40 + c * 8] = wb;
    }
    __syncthreads();
    short8v af[4], bf[4];
#pragma unroll
    for (int i = 0; i < 4; ++i)
      af[i] = *(const short8v*)&As[(wr + i * 16 + mloc) * 40 + quad * 8];
#pragma unroll
    for (int j = 0; j < 4; ++j)
      bf[j] = *(const short8v*)&Bs[(wc + j * 16 + mloc) * 40 + quad * 8];
#pragma unroll
    for (int i = 0; i < 4; ++i)
#pragma unroll
      for (int j = 0; j < 4; ++j)
        acc[i][j] = __builtin_amdgcn_mfma_f32_16x16x32_bf16(af[i], bf[j], acc[i][j], 0, 0, 0);
  }

  float bv[4] = {0.f, 0.f, 0.f, 0.f};
  if (EPI >= 1) {
#pragma unroll
    for (int j = 0; j < 4; ++j) bv[j] = bias[bn + wc + j * 16 + mloc];
  }
#pragma unroll
  for (int i = 0; i < 4; ++i) {
    int gr0 = bm + wr + i * 16 + quad * 4;
#pragma unroll
    for (int j = 0; j < 4; ++j) {
      int gc = bn + wc + j * 16 + mloc;
#pragma unroll
      for (int reg = 0; reg < 4; ++reg) {
        float v = acc[i][j][reg];
        size_t off = (size_t)(gr0 + reg) * Nd + gc;
        if (EPI == 0) {
          ((unsigned short*)outp)[off] = f2bu(v);
        } else if (EPI == 1) {
          ((float*)outp)[off] = v + bv[j] + res[off];
        } else {
          v += bv[j];
          v = 0.5f * v * (1.0f + erff(v * 0.70710678f));
          ((unsigned short*)outp)[off] = f2bu(v);
        }
      }
    }
  }
}

// ---------------------------------------------------------------------------
// K12: MFMA flash cross-attention with token-score bias.
// grid (H_, B_), block 256 (4 waves; wave w owns Q rows 16w..16w+15)
// Q,K,V bf16; softmax fp32 online per-wave; P round-trips LDS as bf16.
// ---------------------------------------------------------------------------
__global__ __launch_bounds__(256) void k_attn(const bf16* __restrict__ qb,
    const bf16* __restrict__ kb, const bf16* __restrict__ vb,
    const float* __restrict__ ts, float* __restrict__ aout)
{
  int h = blockIdx.x, b = blockIdx.y;
  int tid = threadIdx.x;
  __shared__ __align__(16) unsigned short Qs[64 * 100];
  __shared__ __align__(16) unsigned short Ks[64 * 100];
  __shared__ __align__(16) unsigned short Vt[96 * 72];   // transposed V tile
  __shared__ __align__(16) unsigned short Ps[64 * 72];
  __shared__ float tsb[64];
  const unsigned short* Qu = (const unsigned short*)qb;
  const unsigned short* Ku = (const unsigned short*)kb;
  const unsigned short* Vu = (const unsigned short*)vb;

  int wv = tid >> 6, lane = tid & 63;
  int mloc = lane & 15, quad = lane >> 4;

  // stage Q (64x96)
  for (int idx = tid; idx < 1536; idx += 256) {
    int r = idx / 24, c = idx % 24;
    *(ushort4*)&Qs[r * 100 + c * 4] =
        *(const ushort4*)(Qu + (size_t)(b * 64 + r) * D_ + h * 96 + c * 4);
  }

  floatx4 acco[6];
#pragma unroll
  for (int dt = 0; dt < 6; ++dt) acco[dt] = (floatx4){0.f, 0.f, 0.f, 0.f};
  float m_prev[4] = {-1e30f, -1e30f, -1e30f, -1e30f};
  float l_run[4]  = {0.f, 0.f, 0.f, 0.f};

  for (int jt = 0; jt < 9; ++jt) {
    int j0 = jt * 64;
    __syncthreads();   // prior-iter reads done (and Q staged, iter 0)
    // stage K tile (64x96)
    for (int idx = tid; idx < 1536; idx += 256) {
      int r = idx / 24, c = idx % 24;
      *(ushort4*)&Ks[r * 100 + c * 4] =
          *(const ushort4*)(Ku + (size_t)(b * N_ + j0 + r) * D_ + h * 96 + c * 4);
    }
    // stage V tile transposed via 4x4 register blocks
    for (int idx = tid; idx < 384; idx += 256) {
      int jb = idx / 24, db = idx % 24;
      const unsigned short* vp = Vu + (size_t)(b * N_ + j0 + jb * 4) * D_ + h * 96 + db * 4;
      ushort4 r0 = *(const ushort4*)(vp);
      ushort4 r1 = *(const ushort4*)(vp + D_);
      ushort4 r2 = *(const ushort4*)(vp + 2 * D_);
      ushort4 r3 = *(const ushort4*)(vp + 3 * D_);
      ushort4 c0 = {r0.x, r1.x, r2.x, r3.x};
      ushort4 c1 = {r0.y, r1.y, r2.y, r3.y};
      ushort4 c2 = {r0.z, r1.z, r2.z, r3.z};
      ushort4 c3 = {r0.w, r1.w, r2.w, r3.w};
      *(ushort4*)&Vt[(db * 4 + 0) * 72 + jb * 4] = c0;
      *(ushort4*)&Vt[(db * 4 + 1) * 72 + jb * 4] = c1;
      *(ushort4*)&Vt[(db * 4 + 2) * 72 + jb * 4] = c2;
      *(ushort4*)&Vt[(db * 4 + 3) * 72 + jb * 4] = c3;
    }
    if (tid < 64) tsb[tid] = ts[b * N_ + j0 + tid];
    __syncthreads();

    // S = Q K^T  (wave rows 16wv.., 4 col-tiles of 16 keys)
    floatx4 accs[4];
#pragma unroll
    for (int j = 0; j < 4; ++j) accs[j] = (floatx4){0.f, 0.f, 0.f, 0.f};
#pragma unroll
    for (int kc = 0; kc < 3; ++kc) {
      short8v qf = *(const short8v*)&Qs[(wv * 16 + mloc) * 100 + kc * 32 + quad * 8];
#pragma unroll
      for (int jt2 = 0; jt2 < 4; ++jt2) {
        short8v kf = *(const short8v*)&Ks[(jt2 * 16 + mloc) * 100 + kc * 32 + quad * 8];
        accs[jt2] = __builtin_amdgcn_mfma_f32_16x16x32_bf16(qf, kf, accs[jt2], 0, 0, 0);
      }
    }
    float tsv[4];
#pragma unroll
    for (int jt2 = 0; jt2 < 4; ++jt2) tsv[jt2] = tsb[jt2 * 16 + mloc];

    // online softmax per row (row = quad*4 + r within the wave's 16)
#pragma unroll
    for (int r = 0; r < 4; ++r) {
      float sv[4];
      float mx = -1e30f;
#pragma unroll
      for (int jt2 = 0; jt2 < 4; ++jt2) {
        sv[jt2] = accs[jt2][r] * SCALE_ + tsv[jt2];
        mx = fmaxf(mx, sv[jt2]);
      }
      mx = fmaxf(mx, __shfl_xor(mx, 1));
      mx = fmaxf(mx, __shfl_xor(mx, 2));
      mx = fmaxf(mx, __shfl_xor(mx, 4));
      mx = fmaxf(mx, __shfl_xor(mx, 8));
      float mnew = fmaxf(m_prev[r], mx);
      float alpha = expf(m_prev[r] - mnew);
      float rs = 0.f;
#pragma unroll
      for (int jt2 = 0; jt2 < 4; ++jt2) {
        float p = expf(sv[jt2] - mnew);
        rs += p;
        Ps[(wv * 16 + quad * 4 + r) * 72 + jt2 * 16 + mloc] = f2bu(p);
      }
      rs += __shfl_xor(rs, 1); rs += __shfl_xor(rs, 2);
      rs += __shfl_xor(rs, 4); rs += __shfl_xor(rs, 8);
      l_run[r] = l_run[r] * alpha + rs;
      m_prev[r] = mnew;
#pragma unroll
      for (int dt = 0; dt < 6; ++dt) acco[dt][r] *= alpha;
    }

    // O += P V  (P rows are wave-private: no barrier needed)
#pragma unroll
    for (int jc = 0; jc < 2; ++jc) {
      short8v pf = *(const short8v*)&Ps[(wv * 16 + mloc) * 72 + jc * 32 + quad * 8];
#pragma unroll
      for (int dt = 0; dt < 6; ++dt) {
        short8v vf = *(const short8v*)&Vt[(dt * 16 + mloc) * 72 + jc * 32 + quad * 8];
        acco[dt] = __builtin_amdgcn_mfma_f32_16x16x32_bf16(pf, vf, acco[dt], 0, 0, 0);
      }
    }
  }

  float linv[4];
#pragma unroll
  for (int r = 0; r < 4; ++r) linv[r] = 1.0f / l_run[r];
#pragma unroll
  for (int dt = 0; dt < 6; ++dt)
#pragma unroll
    for (int r = 0; r < 4; ++r)
      aout[(size_t)(b * 64 + wv * 16 + quad * 4 + r) * D_ + h * 96 + dt * 16 + mloc] =
          acco[dt][r] * linv[r];
}

// ---------------------------------------------------------------------------
// K14: LayerNorm2 (fp32 in -> fp32 out)
// ---------------------------------------------------------------------------
__global__ __launch_bounds__(256) void k_ln2(const float* __restrict__ f,
    const float* __restrict__ g, const float* __restrict__ bt, float* __restrict__ out)
{
  int row = blockIdx.x, tid = threadIdx.x;
  const float* fr = f + (size_t)row * D_;
  float v0 = fr[tid], v1 = fr[tid + 256], v2 = fr[tid + 512];
  __shared__ float r1[256], r2[256];
  r1[tid] = v0 + v1 + v2;
  r2[tid] = v0 * v0 + v1 * v1 + v2 * v2;
  __syncthreads();
  for (int o = 128; o > 0; o >>= 1) {
    if (tid < o) { r1[tid] += r1[tid + o]; r2[tid] += r2[tid + o]; }
    __syncthreads();
  }
  float mean = r1[0] * (1.0f / D_);
  float var  = r2[0] * (1.0f / D_) - mean * mean;
  float rstd = rsqrtf(var + 1e-5f);
  float* oo = out + (size_t)row * D_;
  oo[tid      ] = (v0 - mean) * rstd * g[tid      ] + bt[tid      ];
  oo[tid + 256] = (v1 - mean) * rstd * g[tid + 256] + bt[tid + 256];
  oo[tid + 512] = (v2 - mean) * rstd * g[tid + 512] + bt[tid + 512];
}

// ---------------------------------------------------------------------------
// Launch.
// ---------------------------------------------------------------------------
extern "C" void kernel_launch(void* const* d_in, const int* in_sizes, int n_in,
                              void* d_out, int out_size, void* d_ws, size_t ws_size,
                              hipStream_t stream)
{
  (void)in_sizes; (void)n_in; (void)out_size; (void)ws_size;
  const float* x    = (const float*)d_in[0];
  const float* nois = (const float*)d_in[1];
  const float* n1g  = (const float*)d_in[2];
  const float* n1b  = (const float*)d_in[3];
  const float* sw   = (const float*)d_in[4];
  const float* sb   = (const float*)d_in[5];
  const float* wq   = (const float*)d_in[6];
  const float* wk   = (const float*)d_in[7];
  const float* wv   = (const float*)d_in[8];
  const float* pw   = (const float*)d_in[9];
  const float* pb   = (const float*)d_in[10];
  const float* n2g  = (const float*)d_in[11];
  const float* n2b  = (const float*)d_in[12];
  const float* f1w  = (const float*)d_in[13];
  const float* f1b  = (const float*)d_in[14];
  const float* f2w  = (const float*)d_in[15];
  const float* f2b  = (const float*)d_in[16];

  float* ws    = (float*)d_ws;
  float* XN    = ws;
  float* RG    = XN + (size_t)NB_ * D_;
  float* QIN   = RG + (size_t)NB_ * D_;
  float* FEAT  = QIN + (size_t)ML_ * D_;
  float* AOUT  = FEAT + (size_t)ML_ * D_;
  float* QBUF  = AOUT + (size_t)ML_ * D_;
  float* P     = QBUF + (size_t)ML_ * D_;
  bf16*  QB16  = (bf16*)P;             P += (size_t)ML_ * D_ / 2;
  bf16*  WTQ   = (bf16*)P;             P += (size_t)D_ * D_ / 2;
  bf16*  WTK   = (bf16*)P;             P += (size_t)D_ * D_ / 2;
  bf16*  WTV   = (bf16*)P;             P += (size_t)D_ * D_ / 2;
  bf16*  WTP   = (bf16*)P;             P += (size_t)D_ * D_ / 2;
  bf16*  WT1   = (bf16*)P;             P += (size_t)D_ * 4 * D_ / 2;
  bf16*  WT2   = (bf16*)P;             P += (size_t)D_ * 4 * D_ / 2;
  float* TS    = P;
  float* SQ    = TS + NB_;
  float* DEN   = SQ + NB_;
  float* SCORE = DEN + NB_;
  float* DMAX  = SCORE + NB_;
  int*   IDXD  = (int*)(DMAX + 64);
  int*   IDXC  = IDXD + ML_;
  float* DM    = RG;                      // phase 1
  bf16*  KB    = (bf16*)RG;               // phase 2
  bf16*  VB    = KB + (size_t)NB_ * D_;
  bf16*  HID   = (bf16*)RG;               // phase 3 (bf16 [4096][3072])

  hipMemsetAsync(DMAX, 0, 64 * sizeof(float), stream);
  k_wt<<<dim3(24, 24), 256, 0, stream>>>(wq, WTQ, D_, D_);
  k_wt<<<dim3(24, 24), 256, 0, stream>>>(wk, WTK, D_, D_);
  k_wt<<<dim3(24, 24), 256, 0, stream>>>(wv, WTV, D_, D_);
  k_wt<<<dim3(24, 24), 256, 0, stream>>>(pw, WTP, D_, D_);
  k_wt<<<dim3(24, 96), 256, 0, stream>>>(f1w, WT1, D_, 4 * D_);
  k_wt<<<dim3(96, 24), 256, 0, stream>>>(f2w, WT2, 4 * D_, D_);

  k_ln1<<<NB_, 256, 0, stream>>>(x, n1g, n1b, sw, sb, XN, TS, SQ);
  k_dm<<<dim3(15, B_), 256, 0, stream>>>(XN, SQ, DM);
  k_density<<<NB_, 64, 0, stream>>>(DM, nois, DEN, DMAX);
  k_dist<<<NB_, 64, 0, stream>>>(DM, DEN, DMAX, SCORE);
  k_topL<<<B_, 256, 0, stream>>>(SCORE, IDXD);
  k_assign<<<B_, 576, 0, stream>>>(DM, IDXD, IDXC);
  k_setcenters<<<B_, 64, 0, stream>>>(IDXD, IDXC);
  k_merge<<<ML_, 256, 0, stream>>>(XN, TS, IDXC, QIN);

  k_mgemm<0, 0><<<dim3(ML_ / 128, D_ / 128), 256, 0, stream>>>(
      QIN, WTQ, nullptr, nullptr, QB16, ML_, D_, D_);
  k_mgemm<0, 0><<<dim3(NB_ / 128, D_ / 128), 256, 0, stream>>>(
      XN, WTK, nullptr, nullptr, KB, NB_, D_, D_);
  k_mgemm<0, 0><<<dim3(NB_ / 128, D_ / 128), 256, 0, stream>>>(
      XN, WTV, nullptr, nullptr, VB, NB_, D_, D_);
  k_attn<<<dim3(H_, B_), 256, 0, stream>>>(QB16, KB, VB, TS, AOUT);
  k_mgemm<1, 0><<<dim3(ML_ / 128, D_ / 128), 256, 0, stream>>>(
      AOUT, WTP, pb, QIN, FEAT, ML_, D_, D_);
  k_ln2<<<ML_, 256, 0, stream>>>(FEAT, n2g, n2b, QBUF);
  k_mgemm<2, 0><<<dim3(ML_ / 128, (4 * D_) / 128), 256, 0, stream>>>(
      QBUF, WT1, f1b, nullptr, HID, ML_, 4 * D_, D_);
  k_mgemm<1, 1><<<dim3(ML_ / 128, D_ / 128), 256, 0, stream>>>(
      HID, WT2, f2b, FEAT, d_out, ML_, D_, 4 * D_);
}

// Round 5
// 1441.909 us; speedup vs baseline: 1.0227x; 1.0227x over previous
//
#include <hip/hip_runtime.h>
#include <hip/hip_bf16.h>
#include <math.h>

// Problem constants
#define B_   64
#define N_   576
#define D_   768
#define L_   64
#define H_   8
#define HD_  96
#define NB_  (B_*N_)    // 36864 rows
#define ML_  (B_*L_)    // 4096 rows
#define SCALE_ 0.10206207f          // 96^-0.5
#define INV_SQRT_D_ 0.03608439182f  // 1/sqrt(768)

typedef __hip_bfloat16 bf16;
typedef __attribute__((ext_vector_type(8))) short short8v;   // 8 bf16 (4 VGPRs)
typedef __attribute__((ext_vector_type(4))) float floatx4;   // MFMA C/D

__device__ __forceinline__ float u2f(unsigned short u) { return __uint_as_float(((unsigned)u) << 16); }
__device__ __forceinline__ unsigned short f2bu(float f) {
  bf16 h = __float2bfloat16(f);
  return *(unsigned short*)&h;
}

// ---------------------------------------------------------------------------
// K1: LayerNorm1 (fp32 in -> fp32 out) + token_score + row sum-of-squares
// ---------------------------------------------------------------------------
__global__ __launch_bounds__(256) void k_ln1(const float* __restrict__ x,
    const float* __restrict__ g, const float* __restrict__ bt,
    const float* __restrict__ sw, const float* __restrict__ sb,
    float* __restrict__ xn, float* __restrict__ ts, float* __restrict__ sq)
{
  int row = blockIdx.x, tid = threadIdx.x;
  const float* xr = x + (size_t)row * D_;
  float v0 = xr[tid], v1 = xr[tid + 256], v2 = xr[tid + 512];
  __shared__ float r1[256], r2[256];
  r1[tid] = v0 + v1 + v2;
  r2[tid] = v0 * v0 + v1 * v1 + v2 * v2;
  __syncthreads();
  for (int o = 128; o > 0; o >>= 1) {
    if (tid < o) { r1[tid] += r1[tid + o]; r2[tid] += r2[tid + o]; }
    __syncthreads();
  }
  float mean = r1[0] * (1.0f / D_);
  float var  = r2[0] * (1.0f / D_) - mean * mean;
  float rstd = rsqrtf(var + 1e-5f);
  __syncthreads();
  float o0 = (v0 - mean) * rstd * g[tid      ] + bt[tid      ];
  float o1 = (v1 - mean) * rstd * g[tid + 256] + bt[tid + 256];
  float o2 = (v2 - mean) * rstd * g[tid + 512] + bt[tid + 512];
  float* xo = xn + (size_t)row * D_;
  xo[tid] = o0; xo[tid + 256] = o1; xo[tid + 512] = o2;
  r1[tid] = o0 * sw[tid] + o1 * sw[tid + 256] + o2 * sw[tid + 512];
  r2[tid] = o0 * o0 + o1 * o1 + o2 * o2;
  __syncthreads();
  for (int o = 128; o > 0; o >>= 1) {
    if (tid < o) { r1[tid] += r1[tid + o]; r2[tid] += r2[tid + o]; }
    __syncthreads();
  }
  if (tid == 0) { ts[row] = r1[0] + sb[0]; sq[row] = r2[0]; }
}

// ---------------------------------------------------------------------------
// K2: pairwise distance matrix (fp32 — feeds discrete clustering; keep exact)
// 128x64 tile, 8x4 microtile (row-split: rows ty*4+{0..3} and 64+ty*4+{0..3}).
// 25 blocks/batch covering j-tile >= 2*i-tile (upper triangle); both
// directions written vectorized (float4). LDS patterns conflict-free:
// B-frag read tx*4 = 2-way (free, m136); A-frag reads are 16-lane broadcasts.
// grid (25, B_), block 256
// ---------------------------------------------------------------------------
__global__ __launch_bounds__(256) void k_dm(const float* __restrict__ xn,
    const float* __restrict__ sq, float* __restrict__ dm)
{
  int b = blockIdx.y;
  int p = blockIdx.x, ri = 0;
  {
    int rem = 9;
    while (p >= rem) { p -= rem; rem -= 2; ri++; }
  }
  int cj = 2 * ri + p;                        // col tile (64-wide), 0..8
  __shared__ float AsT[16][132];
  __shared__ float BsT[16][68];
  int tid = threadIdx.x;
  int ty = tid >> 4, tx = tid & 15;
  int am = tid >> 1, ah = (tid & 1) * 8;      // A staging: row am, k ah..ah+7
  int bm2 = tid >> 2, bh = (tid & 3) * 4;     // B staging: row bm2, k bh..bh+3
  int ra = ri * 128 + am; if (ra > 575) ra = 575;
  int rb = cj * 64 + bm2;
  const float* Xb = xn + (size_t)b * N_ * D_;
  const float* Arow = Xb + (size_t)ra * D_ + ah;
  const float* Brow = Xb + (size_t)rb * D_ + bh;
  float acc[8][4] = {};
  for (int kt = 0; kt < D_; kt += 16) {
    float4 a0 = *(const float4*)(Arow + kt);
    float4 a1 = *(const float4*)(Arow + kt + 4);
    float4 b0 = *(const float4*)(Brow + kt);
    __syncthreads();
    AsT[ah + 0][am] = a0.x; AsT[ah + 1][am] = a0.y; AsT[ah + 2][am] = a0.z; AsT[ah + 3][am] = a0.w;
    AsT[ah + 4][am] = a1.x; AsT[ah + 5][am] = a1.y; AsT[ah + 6][am] = a1.z; AsT[ah + 7][am] = a1.w;
    BsT[bh + 0][bm2] = b0.x; BsT[bh + 1][bm2] = b0.y; BsT[bh + 2][bm2] = b0.z; BsT[bh + 3][bm2] = b0.w;
    __syncthreads();
#pragma unroll
    for (int kk = 0; kk < 16; ++kk) {
      float4 av0 = *(const float4*)&AsT[kk][ty * 4];
      float4 av1 = *(const float4*)&AsT[kk][64 + ty * 4];
      float4 bv  = *(const float4*)&BsT[kk][tx * 4];
      float aR[8] = {av0.x, av0.y, av0.z, av0.w, av1.x, av1.y, av1.z, av1.w};
      float bC[4] = {bv.x, bv.y, bv.z, bv.w};
#pragma unroll
      for (int r = 0; r < 8; ++r)
#pragma unroll
        for (int c = 0; c < 4; ++c) acc[r][c] += aR[r] * bC[c];
    }
  }
  const float* sqb = sq + b * N_;
  float* dmb = dm + (size_t)b * N_ * N_;
  int gj0 = cj * 64 + tx * 4;
  float sj[4];
#pragma unroll
  for (int c = 0; c < 4; ++c) sj[c] = sqb[gj0 + c];
  float d[8][4];
#pragma unroll
  for (int r = 0; r < 8; ++r) {
    int gi = ri * 128 + (r >> 2) * 64 + ty * 4 + (r & 3);
    bool ok = gi < N_;
    float si = ok ? sqb[gi] : 0.f;
#pragma unroll
    for (int c = 0; c < 4; ++c) {
      float dd = si + sj[c] - 2.0f * acc[r][c];
      d[r][c] = sqrtf(fmaxf(dd, 0.0f)) * INV_SQRT_D_;
    }
    if (ok) *(float4*)&dmb[(size_t)gi * N_ + gj0] = make_float4(d[r][0], d[r][1], d[r][2], d[r][3]);
  }
  // transposed direction: rows gj, contiguous cols (row-split halves)
  int tb0 = ri * 128 + ty * 4;
  int tb1 = tb0 + 64;
  bool ok1 = tb1 < N_;   // only false for ri==4
#pragma unroll
  for (int c = 0; c < 4; ++c) {
    int gj = gj0 + c;
    *(float4*)&dmb[(size_t)gj * N_ + tb0] = make_float4(d[0][c], d[1][c], d[2][c], d[3][c]);
    if (ok1)
      *(float4*)&dmb[(size_t)gj * N_ + tb1] = make_float4(d[4][c], d[5][c], d[6][c], d[7][c]);
  }
}

// ---------------------------------------------------------------------------
// K3: kNN density + fused per-batch max
// grid NB_, block 64 (one wave per row)
// ---------------------------------------------------------------------------
__global__ __launch_bounds__(64) void k_density(const float* __restrict__ dm,
    const float* __restrict__ noise, float* __restrict__ den,
    float* __restrict__ dmax)
{
  int row = blockIdx.x, lane = threadIdx.x;
  int b = row / N_;
  const float* r = dm + (size_t)row * N_;
  float a0 = 1e30f, a1 = 1e30f, a2 = 1e30f, a3 = 1e30f, a4 = 1e30f;
  float mx = 0.0f;
  auto ins5 = [&](float xv) {
    a4 = fminf(a4, xv);
    float t;
    t = fminf(a3, a4); a4 = fmaxf(a3, a4); a3 = t;
    t = fminf(a2, a3); a3 = fmaxf(a2, a3); a2 = t;
    t = fminf(a1, a2); a2 = fmaxf(a1, a2); a1 = t;
    t = fminf(a0, a1); a1 = fmaxf(a0, a1); a0 = t;
  };
#pragma unroll
  for (int t = 0; t < 9; ++t) {
    float v = r[lane + 64 * t];
    ins5(v);
    mx = fmaxf(mx, v);
  }
  for (int m = 1; m < 64; m <<= 1) {
    float b0 = __shfl_xor(a0, m), b1 = __shfl_xor(a1, m), b2 = __shfl_xor(a2, m);
    float b3 = __shfl_xor(a3, m), b4 = __shfl_xor(a4, m);
    ins5(b0); ins5(b1); ins5(b2); ins5(b3); ins5(b4);
    mx = fmaxf(mx, __shfl_xor(mx, m));
  }
  if (lane == 0) {
    float ms = (a0 * a0 + a1 * a1 + a2 * a2 + a3 * a3 + a4 * a4) * 0.2f;
    den[row] = expf(-ms) + noise[row] * 1e-6f;
    atomicMax((unsigned int*)(dmax + b), __float_as_uint(mx));
  }
}

// ---------------------------------------------------------------------------
// K5: dist-to-higher-density + score
// ---------------------------------------------------------------------------
__global__ __launch_bounds__(64) void k_dist(const float* __restrict__ dm,
    const float* __restrict__ den, const float* __restrict__ dmax,
    float* __restrict__ score)
{
  int row = blockIdx.x, lane = threadIdx.x;
  int b = row / N_;
  float di = den[row], dx = dmax[b];
  const float* r = dm + (size_t)row * N_;
  const float* db = den + b * N_;
  float m = dx;
#pragma unroll
  for (int t = 0; t < 9; ++t) {
    int j = lane + 64 * t;
    float v = (db[j] > di) ? r[j] : dx;
    m = fminf(m, v);
  }
  for (int msk = 1; msk < 64; msk <<= 1) m = fminf(m, __shfl_xor(m, msk));
  if (lane == 0) score[row] = m * di;
}

// ---------------------------------------------------------------------------
// K6: top-64 scores per batch
// ---------------------------------------------------------------------------
__global__ __launch_bounds__(256) void k_topL(const float* __restrict__ score,
    int* __restrict__ idxd)
{
  int b = blockIdx.x, tid = threadIdx.x;
  __shared__ float s[N_];
  __shared__ float rv[256];
  __shared__ int   ri[256];
  for (int j = tid; j < N_; j += 256) s[j] = score[b * N_ + j];
  __syncthreads();
  for (int it = 0; it < L_; ++it) {
    float bv = -1e30f; int bi = 1 << 30;
    for (int j = tid; j < N_; j += 256) {
      float v = s[j];
      if (v > bv || (v == bv && j < bi)) { bv = v; bi = j; }
    }
    rv[tid] = bv; ri[tid] = bi; __syncthreads();
    for (int o = 128; o > 0; o >>= 1) {
      if (tid < o) {
        float v2 = rv[tid + o]; int i2 = ri[tid + o];
        if (v2 > rv[tid] || (v2 == rv[tid] && i2 < ri[tid])) { rv[tid] = v2; ri[tid] = i2; }
      }
      __syncthreads();
    }
    if (tid == 0) { idxd[b * L_ + it] = ri[0]; s[ri[0]] = -1e30f; }
    __syncthreads();
  }
}

// ---------------------------------------------------------------------------
// K7: assign tokens to nearest center + center override (fused setcenters)
// ---------------------------------------------------------------------------
__global__ __launch_bounds__(576) void k_assign(const float* __restrict__ dm,
    const int* __restrict__ idxd, int* __restrict__ idxc)
{
  int b = blockIdx.x, n = threadIdx.x;
  __shared__ int ctr[L_];
  if (n < L_) ctr[n] = idxd[b * L_ + n];
  __syncthreads();
  const float* dmb = dm + (size_t)b * N_ * N_;
  float best = 1e30f; int bl = 0;
  for (int l = 0; l < L_; ++l) {
    float v = dmb[(size_t)ctr[l] * N_ + n];
    if (v < best) { best = v; bl = l; }
  }
  idxc[b * N_ + n] = bl;
  __syncthreads();               // order: all assignments before overrides
  if (n < L_) idxc[b * N_ + ctr[n]] = n;
}

// ---------------------------------------------------------------------------
// K8: merger (gather form)
// ---------------------------------------------------------------------------
__global__ __launch_bounds__(256) void k_merge(const float* __restrict__ xn,
    const float* __restrict__ ts, const int* __restrict__ idxc,
    float* __restrict__ qin)
{
  int blk = blockIdx.x;
  int b = blk >> 6, l = blk & 63;
  int tid = threadIdx.x;
  const int* ic = idxc + b * N_;
  const float* tsb = ts + b * N_;
  const float* xb = xn + (size_t)b * N_ * D_;
  float a0 = 0.f, a1 = 0.f, a2 = 0.f, wsum = 0.f;
  for (int n = 0; n < N_; ++n) {
    if (ic[n] == l) {
      float w = expf(tsb[n]);
      wsum += w;
      const float* xr = xb + (size_t)n * D_;
      a0 += w * xr[tid]; a1 += w * xr[tid + 256]; a2 += w * xr[tid + 512];
    }
  }
  float inv = 1.0f / (wsum + 1e-6f);
  float* q = qin + (size_t)blk * D_;
  q[tid] = a0 * inv; q[tid + 256] = a1 * inv; q[tid + 512] = a2 * inv;
}

// ---------------------------------------------------------------------------
// Weight transpose + bf16 cast: W[K,N] fp32 -> WT[N,K] bf16
// ---------------------------------------------------------------------------
__global__ __launch_bounds__(256) void k_wt(const float* __restrict__ W,
    bf16* __restrict__ WT, int K, int N)
{
  __shared__ float t[32][33];
  int k0 = blockIdx.x * 32, n0 = blockIdx.y * 32;
  int tid = threadIdx.x;
  int r = tid >> 3, c4 = (tid & 7) * 4;
  float4 v = *(const float4*)(W + (size_t)(k0 + r) * N + n0 + c4);
  t[r][c4] = v.x; t[r][c4 + 1] = v.y; t[r][c4 + 2] = v.z; t[r][c4 + 3] = v.w;
  __syncthreads();
  unsigned short* o = (unsigned short*)WT;
  ushort4 s4;
  s4.x = f2bu(t[c4 + 0][r]); s4.y = f2bu(t[c4 + 1][r]);
  s4.z = f2bu(t[c4 + 2][r]); s4.w = f2bu(t[c4 + 3][r]);
  *(ushort4*)(o + (size_t)(n0 + r) * K + k0 + c4) = s4;
}

// ---------------------------------------------------------------------------
// MFMA GEMM: C[M,N] = epilogue(A[M,K] @ WT[N,K]^T), bf16 MFMA, fp32 accum.
// ---------------------------------------------------------------------------
template<int EPI, int ASRC>
__global__ __launch_bounds__(256) void k_mgemm(const void* __restrict__ Ap_,
    const bf16* __restrict__ Wt, const float* __restrict__ bias,
    const float* __restrict__ res, void* __restrict__ outp,
    int M, int Nd, int Kd)
{
  __shared__ __align__(16) unsigned short As[128 * 40];
  __shared__ __align__(16) unsigned short Bs[128 * 40];
  int tid = threadIdx.x;
  int bm = blockIdx.x * 128, bn = blockIdx.y * 128;
  int wave = tid >> 6, lane = tid & 63;
  int wr = (wave >> 1) * 64, wc = (wave & 1) * 64;
  int mloc = lane & 15, quad = lane >> 4;

  floatx4 acc[4][4];
#pragma unroll
  for (int i = 0; i < 4; ++i)
#pragma unroll
    for (int j = 0; j < 4; ++j)
      acc[i][j] = (floatx4){0.f, 0.f, 0.f, 0.f};

  const unsigned short* Wu = (const unsigned short*)Wt;
  for (int kt = 0; kt < Kd; kt += 32) {
    __syncthreads();
#pragma unroll
    for (int it = 0; it < 2; ++it) {
      int idx = tid + it * 256;          // 0..511
      int r = idx >> 2, c = idx & 3;     // row 0..127, 8-elem chunk 0..3
      uint4 pk;
      if (ASRC == 0) {
        const float* A = (const float*)Ap_;
        const float* ap = A + (size_t)(bm + r) * Kd + kt + c * 8;
        float4 f0 = *(const float4*)ap;
        float4 f1 = *(const float4*)(ap + 4);
        pk.x = (unsigned)f2bu(f0.x) | ((unsigned)f2bu(f0.y) << 16);
        pk.y = (unsigned)f2bu(f0.z) | ((unsigned)f2bu(f0.w) << 16);
        pk.z = (unsigned)f2bu(f1.x) | ((unsigned)f2bu(f1.y) << 16);
        pk.w = (unsigned)f2bu(f1.z) | ((unsigned)f2bu(f1.w) << 16);
      } else {
        const unsigned short* A = (const unsigned short*)Ap_;
        pk = *(const uint4*)(A + (size_t)(bm + r) * Kd + kt + c * 8);
      }
      *(uint4*)&As[r * 40 + c * 8] = pk;
      uint4 wb = *(const uint4*)(Wu + (size_t)(bn + r) * Kd + kt + c * 8);
      *(uint4*)&Bs[r * 40 + c * 8] = wb;
    }
    __syncthreads();
    short8v af[4], bf[4];
#pragma unroll
    for (int i = 0; i < 4; ++i)
      af[i] = *(const short8v*)&As[(wr + i * 16 + mloc) * 40 + quad * 8];
#pragma unroll
    for (int j = 0; j < 4; ++j)
      bf[j] = *(const short8v*)&Bs[(wc + j * 16 + mloc) * 40 + quad * 8];
#pragma unroll
    for (int i = 0; i < 4; ++i)
#pragma unroll
      for (int j = 0; j < 4; ++j)
        acc[i][j] = __builtin_amdgcn_mfma_f32_16x16x32_bf16(af[i], bf[j], acc[i][j], 0, 0, 0);
  }

  float bv[4] = {0.f, 0.f, 0.f, 0.f};
  if (EPI >= 1) {
#pragma unroll
    for (int j = 0; j < 4; ++j) bv[j] = bias[bn + wc + j * 16 + mloc];
  }
#pragma unroll
  for (int i = 0; i < 4; ++i) {
    int gr0 = bm + wr + i * 16 + quad * 4;
#pragma unroll
    for (int j = 0; j < 4; ++j) {
      int gc = bn + wc + j * 16 + mloc;
#pragma unroll
      for (int reg = 0; reg < 4; ++reg) {
        float v = acc[i][j][reg];
        size_t off = (size_t)(gr0 + reg) * Nd + gc;
        if (EPI == 0) {
          ((unsigned short*)outp)[off] = f2bu(v);
        } else if (EPI == 1) {
          ((float*)outp)[off] = v + bv[j] + res[off];
        } else {
          v += bv[j];
          v = 0.5f * v * (1.0f + erff(v * 0.70710678f));
          ((unsigned short*)outp)[off] = f2bu(v);
        }
      }
    }
  }
}

// ---------------------------------------------------------------------------
// K12: MFMA flash cross-attention with token-score bias.
// grid (H_, B_), block 256 (4 waves; wave w owns Q rows 16w..16w+15)
// LDS strides de-conflicted: Q/K rows 108 ushorts (54 dw -> distinct even
// start banks across mloc), V^T/P rows 76 ushorts (38 dw).
// ---------------------------------------------------------------------------
__global__ __launch_bounds__(256) void k_attn(const bf16* __restrict__ qb,
    const bf16* __restrict__ kb, const bf16* __restrict__ vb,
    const float* __restrict__ ts, float* __restrict__ aout)
{
  int h = blockIdx.x, b = blockIdx.y;
  int tid = threadIdx.x;
  __shared__ __align__(16) unsigned short Qs[64 * 108];
  __shared__ __align__(16) unsigned short Ks[64 * 108];
  __shared__ __align__(16) unsigned short Vt[96 * 76];   // transposed V tile
  __shared__ __align__(16) unsigned short Ps[64 * 76];
  __shared__ float tsb[64];
  const unsigned short* Qu = (const unsigned short*)qb;
  const unsigned short* Ku = (const unsigned short*)kb;
  const unsigned short* Vu = (const unsigned short*)vb;

  int wv = tid >> 6, lane = tid & 63;
  int mloc = lane & 15, quad = lane >> 4;

  // stage Q (64x96)
  for (int idx = tid; idx < 1536; idx += 256) {
    int r = idx / 24, c = idx % 24;
    *(ushort4*)&Qs[r * 108 + c * 4] =
        *(const ushort4*)(Qu + (size_t)(b * 64 + r) * D_ + h * 96 + c * 4);
  }

  floatx4 acco[6];
#pragma unroll
  for (int dt = 0; dt < 6; ++dt) acco[dt] = (floatx4){0.f, 0.f, 0.f, 0.f};
  float m_prev[4] = {-1e30f, -1e30f, -1e30f, -1e30f};
  float l_run[4]  = {0.f, 0.f, 0.f, 0.f};

  for (int jt = 0; jt < 9; ++jt) {
    int j0 = jt * 64;
    __syncthreads();   // prior-iter reads done (and Q staged, iter 0)
    // stage K tile (64x96)
    for (int idx = tid; idx < 1536; idx += 256) {
      int r = idx / 24, c = idx % 24;
      *(ushort4*)&Ks[r * 108 + c * 4] =
          *(const ushort4*)(Ku + (size_t)(b * N_ + j0 + r) * D_ + h * 96 + c * 4);
    }
    // stage V tile transposed via 4x4 register blocks
    for (int idx = tid; idx < 384; idx += 256) {
      int jb = idx / 24, db = idx % 24;
      const unsigned short* vp = Vu + (size_t)(b * N_ + j0 + jb * 4) * D_ + h * 96 + db * 4;
      ushort4 r0 = *(const ushort4*)(vp);
      ushort4 r1 = *(const ushort4*)(vp + D_);
      ushort4 r2 = *(const ushort4*)(vp + 2 * D_);
      ushort4 r3 = *(const ushort4*)(vp + 3 * D_);
      ushort4 c0 = {r0.x, r1.x, r2.x, r3.x};
      ushort4 c1 = {r0.y, r1.y, r2.y, r3.y};
      ushort4 c2 = {r0.z, r1.z, r2.z, r3.z};
      ushort4 c3 = {r0.w, r1.w, r2.w, r3.w};
      *(ushort4*)&Vt[(db * 4 + 0) * 76 + jb * 4] = c0;
      *(ushort4*)&Vt[(db * 4 + 1) * 76 + jb * 4] = c1;
      *(ushort4*)&Vt[(db * 4 + 2) * 76 + jb * 4] = c2;
      *(ushort4*)&Vt[(db * 4 + 3) * 76 + jb * 4] = c3;
    }
    if (tid < 64) tsb[tid] = ts[b * N_ + j0 + tid];
    __syncthreads();

    // S = Q K^T  (wave rows 16wv.., 4 col-tiles of 16 keys)
    floatx4 accs[4];
#pragma unroll
    for (int j = 0; j < 4; ++j) accs[j] = (floatx4){0.f, 0.f, 0.f, 0.f};
#pragma unroll
    for (int kc = 0; kc < 3; ++kc) {
      short8v qf = *(const short8v*)&Qs[(wv * 16 + mloc) * 108 + kc * 32 + quad * 8];
#pragma unroll
      for (int jt2 = 0; jt2 < 4; ++jt2) {
        short8v kf = *(const short8v*)&Ks[(jt2 * 16 + mloc) * 108 + kc * 32 + quad * 8];
        accs[jt2] = __builtin_amdgcn_mfma_f32_16x16x32_bf16(qf, kf, accs[jt2], 0, 0, 0);
      }
    }
    float tsv[4];
#pragma unroll
    for (int jt2 = 0; jt2 < 4; ++jt2) tsv[jt2] = tsb[jt2 * 16 + mloc];

    // online softmax per row (row = quad*4 + r within the wave's 16)
#pragma unroll
    for (int r = 0; r < 4; ++r) {
      float sv[4];
      float mx = -1e30f;
#pragma unroll
      for (int jt2 = 0; jt2 < 4; ++jt2) {
        sv[jt2] = accs[jt2][r] * SCALE_ + tsv[jt2];
        mx = fmaxf(mx, sv[jt2]);
      }
      mx = fmaxf(mx, __shfl_xor(mx, 1));
      mx = fmaxf(mx, __shfl_xor(mx, 2));
      mx = fmaxf(mx, __shfl_xor(mx, 4));
      mx = fmaxf(mx, __shfl_xor(mx, 8));
      float mnew = fmaxf(m_prev[r], mx);
      float alpha = expf(m_prev[r] - mnew);
      float rs = 0.f;
#pragma unroll
      for (int jt2 = 0; jt2 < 4; ++jt2) {
        float p = expf(sv[jt2] - mnew);
        rs += p;
        Ps[(wv * 16 + quad * 4 + r) * 76 + jt2 * 16 + mloc] = f2bu(p);
      }
      rs += __shfl_xor(rs, 1); rs += __shfl_xor(rs, 2);
      rs += __shfl_xor(rs, 4); rs += __shfl_xor(rs, 8);
      l_run[r] = l_run[r] * alpha + rs;
      m_prev[r] = mnew;
#pragma unroll
      for (int dt = 0; dt < 6; ++dt) acco[dt][r] *= alpha;
    }

    // O += P V  (P rows are wave-private: no barrier needed)
#pragma unroll
    for (int jc = 0; jc < 2; ++jc) {
      short8v pf = *(const short8v*)&Ps[(wv * 16 + mloc) * 76 + jc * 32 + quad * 8];
#pragma unroll
      for (int dt = 0; dt < 6; ++dt) {
        short8v vf = *(const short8v*)&Vt[(dt * 16 + mloc) * 76 + jc * 32 + quad * 8];
        acco[dt] = __builtin_amdgcn_mfma_f32_16x16x32_bf16(pf, vf, acco[dt], 0, 0, 0);
      }
    }
  }

  float linv[4];
#pragma unroll
  for (int r = 0; r < 4; ++r) linv[r] = 1.0f / l_run[r];
#pragma unroll
  for (int dt = 0; dt < 6; ++dt)
#pragma unroll
    for (int r = 0; r < 4; ++r)
      aout[(size_t)(b * 64 + wv * 16 + quad * 4 + r) * D_ + h * 96 + dt * 16 + mloc] =
          acco[dt][r] * linv[r];
}

// ---------------------------------------------------------------------------
// K14: LayerNorm2 (fp32 in -> fp32 out)
// ---------------------------------------------------------------------------
__global__ __launch_bounds__(256) void k_ln2(const float* __restrict__ f,
    const float* __restrict__ g, const float* __restrict__ bt, float* __restrict__ out)
{
  int row = blockIdx.x, tid = threadIdx.x;
  const float* fr = f + (size_t)row * D_;
  float v0 = fr[tid], v1 = fr[tid + 256], v2 = fr[tid + 512];
  __shared__ float r1[256], r2[256];
  r1[tid] = v0 + v1 + v2;
  r2[tid] = v0 * v0 + v1 * v1 + v2 * v2;
  __syncthreads();
  for (int o = 128; o > 0; o >>= 1) {
    if (tid < o) { r1[tid] += r1[tid + o]; r2[tid] += r2[tid + o]; }
    __syncthreads();
  }
  float mean = r1[0] * (1.0f / D_);
  float var  = r2[0] * (1.0f / D_) - mean * mean;
  float rstd = rsqrtf(var + 1e-5f);
  float* oo = out + (size_t)row * D_;
  oo[tid      ] = (v0 - mean) * rstd * g[tid      ] + bt[tid      ];
  oo[tid + 256] = (v1 - mean) * rstd * g[tid + 256] + bt[tid + 256];
  oo[tid + 512] = (v2 - mean) * rstd * g[tid + 512] + bt[tid + 512];
}

// ---------------------------------------------------------------------------
// Launch.
// ---------------------------------------------------------------------------
extern "C" void kernel_launch(void* const* d_in, const int* in_sizes, int n_in,
                              void* d_out, int out_size, void* d_ws, size_t ws_size,
                              hipStream_t stream)
{
  (void)in_sizes; (void)n_in; (void)out_size; (void)ws_size;
  const float* x    = (const float*)d_in[0];
  const float* nois = (const float*)d_in[1];
  const float* n1g  = (const float*)d_in[2];
  const float* n1b  = (const float*)d_in[3];
  const float* sw   = (const float*)d_in[4];
  const float* sb   = (const float*)d_in[5];
  const float* wq   = (const float*)d_in[6];
  const float* wk   = (const float*)d_in[7];
  const float* wv   = (const float*)d_in[8];
  const float* pw   = (const float*)d_in[9];
  const float* pb   = (const float*)d_in[10];
  const float* n2g  = (const float*)d_in[11];
  const float* n2b  = (const float*)d_in[12];
  const float* f1w  = (const float*)d_in[13];
  const float* f1b  = (const float*)d_in[14];
  const float* f2w  = (const float*)d_in[15];
  const float* f2b  = (const float*)d_in[16];

  float* ws    = (float*)d_ws;
  float* XN    = ws;
  float* RG    = XN + (size_t)NB_ * D_;
  float* QIN   = RG + (size_t)NB_ * D_;
  float* FEAT  = QIN + (size_t)ML_ * D_;
  float* AOUT  = FEAT + (size_t)ML_ * D_;
  float* QBUF  = AOUT + (size_t)ML_ * D_;
  float* P     = QBUF + (size_t)ML_ * D_;
  bf16*  QB16  = (bf16*)P;             P += (size_t)ML_ * D_ / 2;
  bf16*  WTQ   = (bf16*)P;             P += (size_t)D_ * D_ / 2;
  bf16*  WTK   = (bf16*)P;             P += (size_t)D_ * D_ / 2;
  bf16*  WTV   = (bf16*)P;             P += (size_t)D_ * D_ / 2;
  bf16*  WTP   = (bf16*)P;             P += (size_t)D_ * D_ / 2;
  bf16*  WT1   = (bf16*)P;             P += (size_t)D_ * 4 * D_ / 2;
  bf16*  WT2   = (bf16*)P;             P += (size_t)D_ * 4 * D_ / 2;
  float* TS    = P;
  float* SQ    = TS + NB_;
  float* DEN   = SQ + NB_;
  float* SCORE = DEN + NB_;
  float* DMAX  = SCORE + NB_;
  int*   IDXD  = (int*)(DMAX + 64);
  int*   IDXC  = IDXD + ML_;
  float* DM    = RG;                      // phase 1
  bf16*  KB    = (bf16*)RG;               // phase 2
  bf16*  VB    = KB + (size_t)NB_ * D_;
  bf16*  HID   = (bf16*)RG;               // phase 3 (bf16 [4096][3072])

  hipMemsetAsync(DMAX, 0, 64 * sizeof(float), stream);
  k_wt<<<dim3(24, 24), 256, 0, stream>>>(wq, WTQ, D_, D_);
  k_wt<<<dim3(24, 24), 256, 0, stream>>>(wk, WTK, D_, D_);
  k_wt<<<dim3(24, 24), 256, 0, stream>>>(wv, WTV, D_, D_);
  k_wt<<<dim3(24, 24), 256, 0, stream>>>(pw, WTP, D_, D_);
  k_wt<<<dim3(24, 96), 256, 0, stream>>>(f1w, WT1, D_, 4 * D_);
  k_wt<<<dim3(96, 24), 256, 0, stream>>>(f2w, WT2, 4 * D_, D_);

  k_ln1<<<NB_, 256, 0, stream>>>(x, n1g, n1b, sw, sb, XN, TS, SQ);
  k_dm<<<dim3(25, B_), 256, 0, stream>>>(XN, SQ, DM);
  k_density<<<NB_, 64, 0, stream>>>(DM, nois, DEN, DMAX);
  k_dist<<<NB_, 64, 0, stream>>>(DM, DEN, DMAX, SCORE);
  k_topL<<<B_, 256, 0, stream>>>(SCORE, IDXD);
  k_assign<<<B_, 576, 0, stream>>>(DM, IDXD, IDXC);
  k_merge<<<ML_, 256, 0, stream>>>(XN, TS, IDXC, QIN);

  k_mgemm<0, 0><<<dim3(ML_ / 128, D_ / 128), 256, 0, stream>>>(
      QIN, WTQ, nullptr, nullptr, QB16, ML_, D_, D_);
  k_mgemm<0, 0><<<dim3(NB_ / 128, D_ / 128), 256, 0, stream>>>(
      XN, WTK, nullptr, nullptr, KB, NB_, D_, D_);
  k_mgemm<0, 0><<<dim3(NB_ / 128, D_ / 128), 256, 0, stream>>>(
      XN, WTV, nullptr, nullptr, VB, NB_, D_, D_);
  k_attn<<<dim3(H_, B_), 256, 0, stream>>>(QB16, KB, VB, TS, AOUT);
  k_mgemm<1, 0><<<dim3(ML_ / 128, D_ / 128), 256, 0, stream>>>(
      AOUT, WTP, pb, QIN, FEAT, ML_, D_, D_);
  k_ln2<<<ML_, 256, 0, stream>>>(FEAT, n2g, n2b, QBUF);
  k_mgemm<2, 0><<<dim3(ML_ / 128, (4 * D_) / 128), 256, 0, stream>>>(
      QBUF, WT1, f1b, nullptr, HID, ML_, 4 * D_, D_);
  k_mgemm<1, 1><<<dim3(ML_ / 128, D_ / 128), 256, 0, stream>>>(
      HID, WT2, f2b, FEAT, d_out, ML_, D_, 4 * D_);
}

// Round 6
// 1343.083 us; speedup vs baseline: 1.0980x; 1.0736x over previous
//
#include <hip/hip_runtime.h>
#include <hip/hip_bf16.h>
#include <math.h>

// Problem constants
#define B_   64
#define N_   576
#define D_   768
#define L_   64
#define H_   8
#define HD_  96
#define NB_  (B_*N_)    // 36864 rows
#define ML_  (B_*L_)    // 4096 rows
#define SCALE_ 0.10206207f          // 96^-0.5
#define INV_SQRT_D_ 0.03608439182f  // 1/sqrt(768)

typedef __hip_bfloat16 bf16;
typedef __attribute__((ext_vector_type(8))) short short8v;   // 8 bf16 (4 VGPRs)
typedef __attribute__((ext_vector_type(4))) float floatx4;   // MFMA C/D

__device__ __forceinline__ float u2f(unsigned short u) { return __uint_as_float(((unsigned)u) << 16); }
__device__ __forceinline__ unsigned short f2bu(float f) {
  bf16 h = __float2bfloat16(f);
  return *(unsigned short*)&h;
}

// ---------------------------------------------------------------------------
// K1: LayerNorm1 (fp32 in -> fp32 out) + token_score + row sum-of-squares
// ---------------------------------------------------------------------------
__global__ __launch_bounds__(256) void k_ln1(const float* __restrict__ x,
    const float* __restrict__ g, const float* __restrict__ bt,
    const float* __restrict__ sw, const float* __restrict__ sb,
    float* __restrict__ xn, float* __restrict__ ts, float* __restrict__ sq)
{
  int row = blockIdx.x, tid = threadIdx.x;
  const float* xr = x + (size_t)row * D_;
  float v0 = xr[tid], v1 = xr[tid + 256], v2 = xr[tid + 512];
  __shared__ float r1[256], r2[256];
  r1[tid] = v0 + v1 + v2;
  r2[tid] = v0 * v0 + v1 * v1 + v2 * v2;
  __syncthreads();
  for (int o = 128; o > 0; o >>= 1) {
    if (tid < o) { r1[tid] += r1[tid + o]; r2[tid] += r2[tid + o]; }
    __syncthreads();
  }
  float mean = r1[0] * (1.0f / D_);
  float var  = r2[0] * (1.0f / D_) - mean * mean;
  float rstd = rsqrtf(var + 1e-5f);
  __syncthreads();
  float o0 = (v0 - mean) * rstd * g[tid      ] + bt[tid      ];
  float o1 = (v1 - mean) * rstd * g[tid + 256] + bt[tid + 256];
  float o2 = (v2 - mean) * rstd * g[tid + 512] + bt[tid + 512];
  float* xo = xn + (size_t)row * D_;
  xo[tid] = o0; xo[tid + 256] = o1; xo[tid + 512] = o2;
  r1[tid] = o0 * sw[tid] + o1 * sw[tid + 256] + o2 * sw[tid + 512];
  r2[tid] = o0 * o0 + o1 * o1 + o2 * o2;
  __syncthreads();
  for (int o = 128; o > 0; o >>= 1) {
    if (tid < o) { r1[tid] += r1[tid + o]; r2[tid] += r2[tid + o]; }
    __syncthreads();
  }
  if (tid == 0) { ts[row] = r1[0] + sb[0]; sq[row] = r2[0]; }
}

// ---------------------------------------------------------------------------
// K2: pairwise distance matrix (fp32 — feeds discrete clustering; keep exact)
// 128x64 tile, 8x4 microtile, 32-deep K staging (half the barriers of r5),
// register prefetch of next K-stage issued before the FMA burst.
// grid (25, B_), block 256
// ---------------------------------------------------------------------------
__global__ __launch_bounds__(256) void k_dm(const float* __restrict__ xn,
    const float* __restrict__ sq, float* __restrict__ dm)
{
  int b = blockIdx.y;
  int p = blockIdx.x, ri = 0;
  {
    int rem = 9;
    while (p >= rem) { p -= rem; rem -= 2; ri++; }
  }
  int cj = 2 * ri + p;                        // col tile (64-wide), 0..8
  __shared__ float AsT[32][132];
  __shared__ float BsT[32][68];
  int tid = threadIdx.x;
  int ty = tid >> 4, tx = tid & 15;
  int am = tid >> 1, ah = (tid & 1) * 16;     // A staging: row am, k ah..ah+15
  int bm2 = tid >> 2, bh = (tid & 3) * 8;     // B staging: row bm2, k bh..bh+7
  int ra = ri * 128 + am; if (ra > 575) ra = 575;
  int rb = cj * 64 + bm2;
  const float* Xb = xn + (size_t)b * N_ * D_;
  const float* Arow = Xb + (size_t)ra * D_ + ah;
  const float* Brow = Xb + (size_t)rb * D_ + bh;
  // prefetch stage 0
  float4 a0 = *(const float4*)(Arow);
  float4 a1 = *(const float4*)(Arow + 4);
  float4 a2 = *(const float4*)(Arow + 8);
  float4 a3 = *(const float4*)(Arow + 12);
  float4 b0 = *(const float4*)(Brow);
  float4 b1 = *(const float4*)(Brow + 4);
  float acc[8][4] = {};
  for (int kt = 0; kt < D_; kt += 32) {
    __syncthreads();
    AsT[ah +  0][am] = a0.x; AsT[ah +  1][am] = a0.y; AsT[ah +  2][am] = a0.z; AsT[ah +  3][am] = a0.w;
    AsT[ah +  4][am] = a1.x; AsT[ah +  5][am] = a1.y; AsT[ah +  6][am] = a1.z; AsT[ah +  7][am] = a1.w;
    AsT[ah +  8][am] = a2.x; AsT[ah +  9][am] = a2.y; AsT[ah + 10][am] = a2.z; AsT[ah + 11][am] = a2.w;
    AsT[ah + 12][am] = a3.x; AsT[ah + 13][am] = a3.y; AsT[ah + 14][am] = a3.z; AsT[ah + 15][am] = a3.w;
    BsT[bh + 0][bm2] = b0.x; BsT[bh + 1][bm2] = b0.y; BsT[bh + 2][bm2] = b0.z; BsT[bh + 3][bm2] = b0.w;
    BsT[bh + 4][bm2] = b1.x; BsT[bh + 5][bm2] = b1.y; BsT[bh + 6][bm2] = b1.z; BsT[bh + 7][bm2] = b1.w;
    __syncthreads();
    int ktn = (kt + 32 < D_) ? kt + 32 : kt;   // issue next-stage loads early
    a0 = *(const float4*)(Arow + ktn);
    a1 = *(const float4*)(Arow + ktn + 4);
    a2 = *(const float4*)(Arow + ktn + 8);
    a3 = *(const float4*)(Arow + ktn + 12);
    b0 = *(const float4*)(Brow + ktn);
    b1 = *(const float4*)(Brow + ktn + 4);
#pragma unroll
    for (int kk = 0; kk < 32; ++kk) {
      float4 av0 = *(const float4*)&AsT[kk][ty * 4];
      float4 av1 = *(const float4*)&AsT[kk][64 + ty * 4];
      float4 bv  = *(const float4*)&BsT[kk][tx * 4];
      float aR[8] = {av0.x, av0.y, av0.z, av0.w, av1.x, av1.y, av1.z, av1.w};
      float bC[4] = {bv.x, bv.y, bv.z, bv.w};
#pragma unroll
      for (int r = 0; r < 8; ++r)
#pragma unroll
        for (int c = 0; c < 4; ++c) acc[r][c] += aR[r] * bC[c];
    }
  }
  const float* sqb = sq + b * N_;
  float* dmb = dm + (size_t)b * N_ * N_;
  int gj0 = cj * 64 + tx * 4;
  float sj[4];
#pragma unroll
  for (int c = 0; c < 4; ++c) sj[c] = sqb[gj0 + c];
  float d[8][4];
#pragma unroll
  for (int r = 0; r < 8; ++r) {
    int gi = ri * 128 + (r >> 2) * 64 + ty * 4 + (r & 3);
    bool ok = gi < N_;
    float si = ok ? sqb[gi] : 0.f;
#pragma unroll
    for (int c = 0; c < 4; ++c) {
      float dd = si + sj[c] - 2.0f * acc[r][c];
      d[r][c] = sqrtf(fmaxf(dd, 0.0f)) * INV_SQRT_D_;
    }
    if (ok) *(float4*)&dmb[(size_t)gi * N_ + gj0] = make_float4(d[r][0], d[r][1], d[r][2], d[r][3]);
  }
  int tb0 = ri * 128 + ty * 4;
  int tb1 = tb0 + 64;
  bool ok1 = tb1 < N_;
#pragma unroll
  for (int c = 0; c < 4; ++c) {
    int gj = gj0 + c;
    *(float4*)&dmb[(size_t)gj * N_ + tb0] = make_float4(d[0][c], d[1][c], d[2][c], d[3][c]);
    if (ok1)
      *(float4*)&dmb[(size_t)gj * N_ + tb1] = make_float4(d[4][c], d[5][c], d[6][c], d[7][c]);
  }
}

// ---------------------------------------------------------------------------
// K3: kNN density + fused per-batch max
// ---------------------------------------------------------------------------
__global__ __launch_bounds__(64) void k_density(const float* __restrict__ dm,
    const float* __restrict__ noise, float* __restrict__ den,
    float* __restrict__ dmax)
{
  int row = blockIdx.x, lane = threadIdx.x;
  int b = row / N_;
  const float* r = dm + (size_t)row * N_;
  float a0 = 1e30f, a1 = 1e30f, a2 = 1e30f, a3 = 1e30f, a4 = 1e30f;
  float mx = 0.0f;
  auto ins5 = [&](float xv) {
    a4 = fminf(a4, xv);
    float t;
    t = fminf(a3, a4); a4 = fmaxf(a3, a4); a3 = t;
    t = fminf(a2, a3); a3 = fmaxf(a2, a3); a2 = t;
    t = fminf(a1, a2); a2 = fmaxf(a1, a2); a1 = t;
    t = fminf(a0, a1); a1 = fmaxf(a0, a1); a0 = t;
  };
#pragma unroll
  for (int t = 0; t < 9; ++t) {
    float v = r[lane + 64 * t];
    ins5(v);
    mx = fmaxf(mx, v);
  }
  for (int m = 1; m < 64; m <<= 1) {
    float b0 = __shfl_xor(a0, m), b1 = __shfl_xor(a1, m), b2 = __shfl_xor(a2, m);
    float b3 = __shfl_xor(a3, m), b4 = __shfl_xor(a4, m);
    ins5(b0); ins5(b1); ins5(b2); ins5(b3); ins5(b4);
    mx = fmaxf(mx, __shfl_xor(mx, m));
  }
  if (lane == 0) {
    float ms = (a0 * a0 + a1 * a1 + a2 * a2 + a3 * a3 + a4 * a4) * 0.2f;
    den[row] = expf(-ms) + noise[row] * 1e-6f;
    atomicMax((unsigned int*)(dmax + b), __float_as_uint(mx));
  }
}

// ---------------------------------------------------------------------------
// K5: dist-to-higher-density + score
// ---------------------------------------------------------------------------
__global__ __launch_bounds__(64) void k_dist(const float* __restrict__ dm,
    const float* __restrict__ den, const float* __restrict__ dmax,
    float* __restrict__ score)
{
  int row = blockIdx.x, lane = threadIdx.x;
  int b = row / N_;
  float di = den[row], dx = dmax[b];
  const float* r = dm + (size_t)row * N_;
  const float* db = den + b * N_;
  float m = dx;
#pragma unroll
  for (int t = 0; t < 9; ++t) {
    int j = lane + 64 * t;
    float v = (db[j] > di) ? r[j] : dx;
    m = fminf(m, v);
  }
  for (int msk = 1; msk < 64; msk <<= 1) m = fminf(m, __shfl_xor(m, msk));
  if (lane == 0) score[row] = m * di;
}

// ---------------------------------------------------------------------------
// K6: top-64 scores per batch
// ---------------------------------------------------------------------------
__global__ __launch_bounds__(256) void k_topL(const float* __restrict__ score,
    int* __restrict__ idxd)
{
  int b = blockIdx.x, tid = threadIdx.x;
  __shared__ float s[N_];
  __shared__ float rv[256];
  __shared__ int   ri[256];
  for (int j = tid; j < N_; j += 256) s[j] = score[b * N_ + j];
  __syncthreads();
  for (int it = 0; it < L_; ++it) {
    float bv = -1e30f; int bi = 1 << 30;
    for (int j = tid; j < N_; j += 256) {
      float v = s[j];
      if (v > bv || (v == bv && j < bi)) { bv = v; bi = j; }
    }
    rv[tid] = bv; ri[tid] = bi; __syncthreads();
    for (int o = 128; o > 0; o >>= 1) {
      if (tid < o) {
        float v2 = rv[tid + o]; int i2 = ri[tid + o];
        if (v2 > rv[tid] || (v2 == rv[tid] && i2 < ri[tid])) { rv[tid] = v2; ri[tid] = i2; }
      }
      __syncthreads();
    }
    if (tid == 0) { idxd[b * L_ + it] = ri[0]; s[ri[0]] = -1e30f; }
    __syncthreads();
  }
}

// ---------------------------------------------------------------------------
// K7: assign tokens to nearest center + center override (fused)
// ---------------------------------------------------------------------------
__global__ __launch_bounds__(576) void k_assign(const float* __restrict__ dm,
    const int* __restrict__ idxd, int* __restrict__ idxc)
{
  int b = blockIdx.x, n = threadIdx.x;
  __shared__ int ctr[L_];
  if (n < L_) ctr[n] = idxd[b * L_ + n];
  __syncthreads();
  const float* dmb = dm + (size_t)b * N_ * N_;
  float best = 1e30f; int bl = 0;
  for (int l = 0; l < L_; ++l) {
    float v = dmb[(size_t)ctr[l] * N_ + n];
    if (v < best) { best = v; bl = l; }
  }
  idxc[b * N_ + n] = bl;
  __syncthreads();
  if (n < L_) idxc[b * N_ + ctr[n]] = n;
}

// ---------------------------------------------------------------------------
// K_cast: XN fp32 -> XN16 bf16 (8 elems/thread, 16B stores)
// ---------------------------------------------------------------------------
__global__ __launch_bounds__(256) void k_cast(const float* __restrict__ in,
    unsigned short* __restrict__ out)
{
  int i = blockIdx.x * 256 + threadIdx.x;
  const float4* pp = (const float4*)in + 2 * (size_t)i;
  float4 f0 = pp[0], f1 = pp[1];
  uint4 pk;
  pk.x = (unsigned)f2bu(f0.x) | ((unsigned)f2bu(f0.y) << 16);
  pk.y = (unsigned)f2bu(f0.z) | ((unsigned)f2bu(f0.w) << 16);
  pk.z = (unsigned)f2bu(f1.x) | ((unsigned)f2bu(f1.y) << 16);
  pk.w = (unsigned)f2bu(f1.z) | ((unsigned)f2bu(f1.w) << 16);
  *((uint4*)out + i) = pk;
}

// ---------------------------------------------------------------------------
// K8: merger (gather form, bf16 inputs, bf16 output)
// ---------------------------------------------------------------------------
__global__ __launch_bounds__(256) void k_merge(const unsigned short* __restrict__ xn16,
    const float* __restrict__ ts, const int* __restrict__ idxc,
    unsigned short* __restrict__ qin16)
{
  int blk = blockIdx.x;
  int b = blk >> 6, l = blk & 63;
  int tid = threadIdx.x;
  const int* ic = idxc + b * N_;
  const float* tsb = ts + b * N_;
  const unsigned short* xb = xn16 + (size_t)b * N_ * D_;
  float a0 = 0.f, a1 = 0.f, a2 = 0.f, wsum = 0.f;
  for (int n = 0; n < N_; ++n) {
    if (ic[n] == l) {
      float w = expf(tsb[n]);
      wsum += w;
      const unsigned short* xr = xb + (size_t)n * D_;
      a0 += w * u2f(xr[tid]); a1 += w * u2f(xr[tid + 256]); a2 += w * u2f(xr[tid + 512]);
    }
  }
  float inv = 1.0f / (wsum + 1e-6f);
  unsigned short* q = qin16 + (size_t)blk * D_;
  q[tid] = f2bu(a0 * inv); q[tid + 256] = f2bu(a1 * inv); q[tid + 512] = f2bu(a2 * inv);
}

// ---------------------------------------------------------------------------
// Weight transpose + bf16 cast: W[K,N] fp32 -> WT[N,K] bf16
// ---------------------------------------------------------------------------
__global__ __launch_bounds__(256) void k_wt(const float* __restrict__ W,
    bf16* __restrict__ WT, int K, int N)
{
  __shared__ float t[32][33];
  int k0 = blockIdx.x * 32, n0 = blockIdx.y * 32;
  int tid = threadIdx.x;
  int r = tid >> 3, c4 = (tid & 7) * 4;
  float4 v = *(const float4*)(W + (size_t)(k0 + r) * N + n0 + c4);
  t[r][c4] = v.x; t[r][c4 + 1] = v.y; t[r][c4 + 2] = v.z; t[r][c4 + 3] = v.w;
  __syncthreads();
  unsigned short* o = (unsigned short*)WT;
  ushort4 s4;
  s4.x = f2bu(t[c4 + 0][r]); s4.y = f2bu(t[c4 + 1][r]);
  s4.z = f2bu(t[c4 + 2][r]); s4.w = f2bu(t[c4 + 3][r]);
  *(ushort4*)(o + (size_t)(n0 + r) * K + k0 + c4) = s4;
}

// q/k/v in one dispatch: z selects source; k,v land in WTKV rows 0..767/768..1535
__global__ __launch_bounds__(256) void k_wt3(const float* __restrict__ wq,
    const float* __restrict__ wk, const float* __restrict__ wv,
    bf16* __restrict__ WTQ, bf16* __restrict__ WTKV)
{
  __shared__ float t[32][33];
  int z = blockIdx.z;
  const float* W = (z == 0) ? wq : ((z == 1) ? wk : wv);
  unsigned short* o = (unsigned short*)((z == 0) ? WTQ : WTKV) + ((z == 2) ? 768 * 768 : 0);
  int k0 = blockIdx.x * 32, n0 = blockIdx.y * 32;
  int tid = threadIdx.x;
  int r = tid >> 3, c4 = (tid & 7) * 4;
  float4 v = *(const float4*)(W + (size_t)(k0 + r) * D_ + n0 + c4);
  t[r][c4] = v.x; t[r][c4 + 1] = v.y; t[r][c4 + 2] = v.z; t[r][c4 + 3] = v.w;
  __syncthreads();
  ushort4 s4;
  s4.x = f2bu(t[c4 + 0][r]); s4.y = f2bu(t[c4 + 1][r]);
  s4.z = f2bu(t[c4 + 2][r]); s4.w = f2bu(t[c4 + 3][r]);
  *(ushort4*)(o + (size_t)(n0 + r) * D_ + k0 + c4) = s4;
}

// ---------------------------------------------------------------------------
// MFMA GEMM: C[M,N] = epilogue(A[M,K](bf16) @ WT[N,K]^T), fp32 accum.
// Register-prefetched staging (next K-stage loads issued before MFMA burst).
// EPI 0: bf16 out             1: +bias, +bf16 res -> fp32 out
//     2: +bias, GELU -> bf16  3: +bias, +fp32 res -> fp32 out
// ---------------------------------------------------------------------------
template<int EPI>
__global__ __launch_bounds__(256) void k_mgemm(const bf16* __restrict__ A,
    const bf16* __restrict__ Wt, const float* __restrict__ bias,
    const void* __restrict__ res, void* __restrict__ outp,
    int M, int Nd, int Kd)
{
  __shared__ __align__(16) unsigned short As[128 * 40];
  __shared__ __align__(16) unsigned short Bs[128 * 40];
  int tid = threadIdx.x;
  int bm = blockIdx.x * 128, bn = blockIdx.y * 128;
  int wave = tid >> 6, lane = tid & 63;
  int wr = (wave >> 1) * 64, wc = (wave & 1) * 64;
  int mloc = lane & 15, quad = lane >> 4;

  floatx4 acc[4][4];
#pragma unroll
  for (int i = 0; i < 4; ++i)
#pragma unroll
    for (int j = 0; j < 4; ++j)
      acc[i][j] = (floatx4){0.f, 0.f, 0.f, 0.f};

  const unsigned short* Au = (const unsigned short*)A;
  const unsigned short* Wu = (const unsigned short*)Wt;
  int sr = tid >> 2, sc = (tid & 3) * 8;
  const unsigned short* Ap0 = Au + (size_t)(bm + sr) * Kd + sc;
  const unsigned short* Ap1 = Au + (size_t)(bm + 64 + sr) * Kd + sc;
  const unsigned short* Bp0 = Wu + (size_t)(bn + sr) * Kd + sc;
  const unsigned short* Bp1 = Wu + (size_t)(bn + 64 + sr) * Kd + sc;
  uint4 pa0 = *(const uint4*)(Ap0);
  uint4 pa1 = *(const uint4*)(Ap1);
  uint4 pb0 = *(const uint4*)(Bp0);
  uint4 pb1 = *(const uint4*)(Bp1);

  for (int kt = 0; kt < Kd; kt += 32) {
    __syncthreads();
    *(uint4*)&As[sr * 40 + sc] = pa0;
    *(uint4*)&As[(64 + sr) * 40 + sc] = pa1;
    *(uint4*)&Bs[sr * 40 + sc] = pb0;
    *(uint4*)&Bs[(64 + sr) * 40 + sc] = pb1;
    __syncthreads();
    int ktn = (kt + 32 < Kd) ? kt + 32 : kt;
    pa0 = *(const uint4*)(Ap0 + ktn);
    pa1 = *(const uint4*)(Ap1 + ktn);
    pb0 = *(const uint4*)(Bp0 + ktn);
    pb1 = *(const uint4*)(Bp1 + ktn);
    short8v af[4], bf[4];
#pragma unroll
    for (int i = 0; i < 4; ++i)
      af[i] = *(const short8v*)&As[(wr + i * 16 + mloc) * 40 + quad * 8];
#pragma unroll
    for (int j = 0; j < 4; ++j)
      bf[j] = *(const short8v*)&Bs[(wc + j * 16 + mloc) * 40 + quad * 8];
#pragma unroll
    for (int i = 0; i < 4; ++i)
#pragma unroll
      for (int j = 0; j < 4; ++j)
        acc[i][j] = __builtin_amdgcn_mfma_f32_16x16x32_bf16(af[i], bf[j], acc[i][j], 0, 0, 0);
  }

  float bv[4] = {0.f, 0.f, 0.f, 0.f};
  if (EPI >= 1) {
#pragma unroll
    for (int j = 0; j < 4; ++j) bv[j] = bias[bn + wc + j * 16 + mloc];
  }
#pragma unroll
  for (int i = 0; i < 4; ++i) {
    int gr0 = bm + wr + i * 16 + quad * 4;
#pragma unroll
    for (int j = 0; j < 4; ++j) {
      int gc = bn + wc + j * 16 + mloc;
#pragma unroll
      for (int reg = 0; reg < 4; ++reg) {
        float v = acc[i][j][reg];
        size_t off = (size_t)(gr0 + reg) * Nd + gc;
        if (EPI == 0) {
          ((unsigned short*)outp)[off] = f2bu(v);
        } else if (EPI == 1) {
          ((float*)outp)[off] = v + bv[j] + u2f(((const unsigned short*)res)[off]);
        } else if (EPI == 2) {
          v += bv[j];
          v = 0.5f * v * (1.0f + erff(v * 0.70710678f));
          ((unsigned short*)outp)[off] = f2bu(v);
        } else {
          ((float*)outp)[off] = v + bv[j] + ((const float*)res)[off];
        }
      }
    }
  }
}

// ---------------------------------------------------------------------------
// K12: MFMA flash cross-attention with token-score bias.
// KV interleaved [NB][1536] (k | v); bf16 output.
// ---------------------------------------------------------------------------
__global__ __launch_bounds__(256) void k_attn(const bf16* __restrict__ qb,
    const bf16* __restrict__ kvb, const float* __restrict__ ts,
    unsigned short* __restrict__ aout)
{
  int h = blockIdx.x, b = blockIdx.y;
  int tid = threadIdx.x;
  __shared__ __align__(16) unsigned short Qs[64 * 108];
  __shared__ __align__(16) unsigned short Ks[64 * 108];
  __shared__ __align__(16) unsigned short Vt[96 * 76];
  __shared__ __align__(16) unsigned short Ps[64 * 76];
  __shared__ float tsb[64];
  const unsigned short* Qu = (const unsigned short*)qb;
  const unsigned short* KVu = (const unsigned short*)kvb;

  int wv = tid >> 6, lane = tid & 63;
  int mloc = lane & 15, quad = lane >> 4;

  for (int idx = tid; idx < 1536; idx += 256) {
    int r = idx / 24, c = idx % 24;
    *(ushort4*)&Qs[r * 108 + c * 4] =
        *(const ushort4*)(Qu + (size_t)(b * 64 + r) * D_ + h * 96 + c * 4);
  }

  floatx4 acco[6];
#pragma unroll
  for (int dt = 0; dt < 6; ++dt) acco[dt] = (floatx4){0.f, 0.f, 0.f, 0.f};
  float m_prev[4] = {-1e30f, -1e30f, -1e30f, -1e30f};
  float l_run[4]  = {0.f, 0.f, 0.f, 0.f};

  for (int jt = 0; jt < 9; ++jt) {
    int j0 = jt * 64;
    __syncthreads();
    for (int idx = tid; idx < 1536; idx += 256) {
      int r = idx / 24, c = idx % 24;
      *(ushort4*)&Ks[r * 108 + c * 4] =
          *(const ushort4*)(KVu + (size_t)(b * N_ + j0 + r) * 1536 + h * 96 + c * 4);
    }
    for (int idx = tid; idx < 384; idx += 256) {
      int jb = idx / 24, db = idx % 24;
      const unsigned short* vp = KVu + (size_t)(b * N_ + j0 + jb * 4) * 1536 + 768 + h * 96 + db * 4;
      ushort4 r0 = *(const ushort4*)(vp);
      ushort4 r1 = *(const ushort4*)(vp + 1536);
      ushort4 r2 = *(const ushort4*)(vp + 2 * 1536);
      ushort4 r3 = *(const ushort4*)(vp + 3 * 1536);
      ushort4 c0 = {r0.x, r1.x, r2.x, r3.x};
      ushort4 c1 = {r0.y, r1.y, r2.y, r3.y};
      ushort4 c2 = {r0.z, r1.z, r2.z, r3.z};
      ushort4 c3 = {r0.w, r1.w, r2.w, r3.w};
      *(ushort4*)&Vt[(db * 4 + 0) * 76 + jb * 4] = c0;
      *(ushort4*)&Vt[(db * 4 + 1) * 76 + jb * 4] = c1;
      *(ushort4*)&Vt[(db * 4 + 2) * 76 + jb * 4] = c2;
      *(ushort4*)&Vt[(db * 4 + 3) * 76 + jb * 4] = c3;
    }
    if (tid < 64) tsb[tid] = ts[b * N_ + j0 + tid];
    __syncthreads();

    floatx4 accs[4];
#pragma unroll
    for (int j = 0; j < 4; ++j) accs[j] = (floatx4){0.f, 0.f, 0.f, 0.f};
#pragma unroll
    for (int kc = 0; kc < 3; ++kc) {
      short8v qf = *(const short8v*)&Qs[(wv * 16 + mloc) * 108 + kc * 32 + quad * 8];
#pragma unroll
      for (int jt2 = 0; jt2 < 4; ++jt2) {
        short8v kf = *(const short8v*)&Ks[(jt2 * 16 + mloc) * 108 + kc * 32 + quad * 8];
        accs[jt2] = __builtin_amdgcn_mfma_f32_16x16x32_bf16(qf, kf, accs[jt2], 0, 0, 0);
      }
    }
    float tsv[4];
#pragma unroll
    for (int jt2 = 0; jt2 < 4; ++jt2) tsv[jt2] = tsb[jt2 * 16 + mloc];

#pragma unroll
    for (int r = 0; r < 4; ++r) {
      float sv[4];
      float mx = -1e30f;
#pragma unroll
      for (int jt2 = 0; jt2 < 4; ++jt2) {
        sv[jt2] = accs[jt2][r] * SCALE_ + tsv[jt2];
        mx = fmaxf(mx, sv[jt2]);
      }
      mx = fmaxf(mx, __shfl_xor(mx, 1));
      mx = fmaxf(mx, __shfl_xor(mx, 2));
      mx = fmaxf(mx, __shfl_xor(mx, 4));
      mx = fmaxf(mx, __shfl_xor(mx, 8));
      float mnew = fmaxf(m_prev[r], mx);
      float alpha = expf(m_prev[r] - mnew);
      float rs = 0.f;
#pragma unroll
      for (int jt2 = 0; jt2 < 4; ++jt2) {
        float p = expf(sv[jt2] - mnew);
        rs += p;
        Ps[(wv * 16 + quad * 4 + r) * 76 + jt2 * 16 + mloc] = f2bu(p);
      }
      rs += __shfl_xor(rs, 1); rs += __shfl_xor(rs, 2);
      rs += __shfl_xor(rs, 4); rs += __shfl_xor(rs, 8);
      l_run[r] = l_run[r] * alpha + rs;
      m_prev[r] = mnew;
#pragma unroll
      for (int dt = 0; dt < 6; ++dt) acco[dt][r] *= alpha;
    }

#pragma unroll
    for (int jc = 0; jc < 2; ++jc) {
      short8v pf = *(const short8v*)&Ps[(wv * 16 + mloc) * 76 + jc * 32 + quad * 8];
#pragma unroll
      for (int dt = 0; dt < 6; ++dt) {
        short8v vf = *(const short8v*)&Vt[(dt * 16 + mloc) * 76 + jc * 32 + quad * 8];
        acco[dt] = __builtin_amdgcn_mfma_f32_16x16x32_bf16(pf, vf, acco[dt], 0, 0, 0);
      }
    }
  }

  float linv[4];
#pragma unroll
  for (int r = 0; r < 4; ++r) linv[r] = 1.0f / l_run[r];
#pragma unroll
  for (int dt = 0; dt < 6; ++dt)
#pragma unroll
    for (int r = 0; r < 4; ++r)
      aout[(size_t)(b * 64 + wv * 16 + quad * 4 + r) * D_ + h * 96 + dt * 16 + mloc] =
          f2bu(acco[dt][r] * linv[r]);
}

// ---------------------------------------------------------------------------
// K14: LayerNorm2 (fp32 in -> bf16 out; only consumed by fc1 MFMA GEMM)
// ---------------------------------------------------------------------------
__global__ __launch_bounds__(256) void k_ln2(const float* __restrict__ f,
    const float* __restrict__ g, const float* __restrict__ bt,
    unsigned short* __restrict__ out)
{
  int row = blockIdx.x, tid = threadIdx.x;
  const float* fr = f + (size_t)row * D_;
  float v0 = fr[tid], v1 = fr[tid + 256], v2 = fr[tid + 512];
  __shared__ float r1[256], r2[256];
  r1[tid] = v0 + v1 + v2;
  r2[tid] = v0 * v0 + v1 * v1 + v2 * v2;
  __syncthreads();
  for (int o = 128; o > 0; o >>= 1) {
    if (tid < o) { r1[tid] += r1[tid + o]; r2[tid] += r2[tid + o]; }
    __syncthreads();
  }
  float mean = r1[0] * (1.0f / D_);
  float var  = r2[0] * (1.0f / D_) - mean * mean;
  float rstd = rsqrtf(var + 1e-5f);
  unsigned short* oo = out + (size_t)row * D_;
  oo[tid      ] = f2bu((v0 - mean) * rstd * g[tid      ] + bt[tid      ]);
  oo[tid + 256] = f2bu((v1 - mean) * rstd * g[tid + 256] + bt[tid + 256]);
  oo[tid + 512] = f2bu((v2 - mean) * rstd * g[tid + 512] + bt[tid + 512]);
}

// ---------------------------------------------------------------------------
// Launch. Workspace (float units), ~251 MB peak with lifetime overlays:
//  XN [28.3M]  : fp32 xn; dead after k_cast -> KV bf16 [NB][1536] (113MB exact)
//  RG [21.2M]  : DM (85MB); after assign -> HID bf16 (RG[0..6.29M]) +
//                XN16 bf16 (RG[6.29M..20.45M])
//  FEAT [3.1M] | QIN16 QB16 AOUT16 QBUF16 [1.57M each] | WTs | TS SQ DEN SCORE
// ---------------------------------------------------------------------------
extern "C" void kernel_launch(void* const* d_in, const int* in_sizes, int n_in,
                              void* d_out, int out_size, void* d_ws, size_t ws_size,
                              hipStream_t stream)
{
  (void)in_sizes; (void)n_in; (void)out_size; (void)ws_size;
  const float* x    = (const float*)d_in[0];
  const float* nois = (const float*)d_in[1];
  const float* n1g  = (const float*)d_in[2];
  const float* n1b  = (const float*)d_in[3];
  const float* sw   = (const float*)d_in[4];
  const float* sb   = (const float*)d_in[5];
  const float* wq   = (const float*)d_in[6];
  const float* wk   = (const float*)d_in[7];
  const float* wv   = (const float*)d_in[8];
  const float* pw   = (const float*)d_in[9];
  const float* pb   = (const float*)d_in[10];
  const float* n2g  = (const float*)d_in[11];
  const float* n2b  = (const float*)d_in[12];
  const float* f1w  = (const float*)d_in[13];
  const float* f1b  = (const float*)d_in[14];
  const float* f2w  = (const float*)d_in[15];
  const float* f2b  = (const float*)d_in[16];

  float* ws    = (float*)d_ws;
  float* XN    = ws;                                   // 28,311,552 floats
  float* RG    = XN + (size_t)NB_ * D_;                // 21,233,664 floats
  float* FEAT  = RG + (size_t)B_ * N_ * N_;            // 3,145,728
  float* P     = FEAT + (size_t)ML_ * D_;
  bf16*  QIN16 = (bf16*)P;   P += (size_t)ML_ * D_ / 2;
  bf16*  QB16  = (bf16*)P;   P += (size_t)ML_ * D_ / 2;
  bf16*  AOUT16= (bf16*)P;   P += (size_t)ML_ * D_ / 2;
  bf16*  QBUF16= (bf16*)P;   P += (size_t)ML_ * D_ / 2;
  bf16*  WTQ   = (bf16*)P;   P += (size_t)D_ * D_ / 2;
  bf16*  WTKV  = (bf16*)P;   P += (size_t)D_ * D_;          // 1536x768 bf16
  bf16*  WTP   = (bf16*)P;   P += (size_t)D_ * D_ / 2;
  bf16*  WT1   = (bf16*)P;   P += (size_t)D_ * 4 * D_ / 2;
  bf16*  WT2   = (bf16*)P;   P += (size_t)D_ * 4 * D_ / 2;
  float* TS    = P;
  float* SQ    = TS + NB_;
  float* DEN   = SQ + NB_;
  float* SCORE = DEN + NB_;
  float* DMAX  = SCORE + NB_;
  int*   IDXD  = (int*)(DMAX + 64);
  int*   IDXC  = IDXD + ML_;

  float* DM    = RG;                                   // phase 1
  bf16*  HID   = (bf16*)RG;                            // phase 3 [4096][3072]
  bf16*  XN16  = (bf16*)(RG + (size_t)ML_ * 4 * D_ / 2); // after HID slot
  bf16*  KV    = (bf16*)XN;                            // phase 2 [NB][1536]

  hipMemsetAsync(DMAX, 0, 64 * sizeof(float), stream);
  k_wt3<<<dim3(24, 24, 3), 256, 0, stream>>>(wq, wk, wv, WTQ, WTKV);
  k_wt<<<dim3(24, 24), 256, 0, stream>>>(pw, WTP, D_, D_);
  k_wt<<<dim3(24, 96), 256, 0, stream>>>(f1w, WT1, D_, 4 * D_);
  k_wt<<<dim3(96, 24), 256, 0, stream>>>(f2w, WT2, 4 * D_, D_);

  k_ln1<<<NB_, 256, 0, stream>>>(x, n1g, n1b, sw, sb, XN, TS, SQ);
  k_dm<<<dim3(25, B_), 256, 0, stream>>>(XN, SQ, DM);
  k_density<<<NB_, 64, 0, stream>>>(DM, nois, DEN, DMAX);
  k_dist<<<NB_, 64, 0, stream>>>(DM, DEN, DMAX, SCORE);
  k_topL<<<B_, 256, 0, stream>>>(SCORE, IDXD);
  k_assign<<<B_, 576, 0, stream>>>(DM, IDXD, IDXC);
  k_cast<<<(NB_ * D_) / 2048, 256, 0, stream>>>(XN, (unsigned short*)XN16);
  k_merge<<<ML_, 256, 0, stream>>>((const unsigned short*)XN16, TS, IDXC,
                                   (unsigned short*)QIN16);

  k_mgemm<0><<<dim3(ML_ / 128, D_ / 128), 256, 0, stream>>>(
      QIN16, WTQ, nullptr, nullptr, QB16, ML_, D_, D_);
  k_mgemm<0><<<dim3(NB_ / 128, 1536 / 128), 256, 0, stream>>>(
      XN16, WTKV, nullptr, nullptr, KV, NB_, 1536, D_);
  k_attn<<<dim3(H_, B_), 256, 0, stream>>>(QB16, KV, TS, (unsigned short*)AOUT16);
  k_mgemm<1><<<dim3(ML_ / 128, D_ / 128), 256, 0, stream>>>(
      AOUT16, WTP, pb, QIN16, FEAT, ML_, D_, D_);
  k_ln2<<<ML_, 256, 0, stream>>>(FEAT, n2g, n2b, (unsigned short*)QBUF16);
  k_mgemm<2><<<dim3(ML_ / 128, (4 * D_) / 128), 256, 0, stream>>>(
      QBUF16, WT1, f1b, nullptr, HID, ML_, 4 * D_, D_);
  k_mgemm<3><<<dim3(ML_ / 128, D_ / 128), 256, 0, stream>>>(
      HID, WT2, f2b, FEAT, d_out, ML_, D_, 4 * D_);
}